// Round 9
// baseline (413.793 us; speedup 1.0000x reference)
//
#include <hip/hip_runtime.h>
#include <hip/hip_bf16.h>

#define HDIM 4096
#define DHEAD 128
#define NQH 32
#define NKVH 8
#define SEQ 2048
#define QKVN 6144  // fused N = 4096 + 1024 + 1024

typedef __bf16 bf16x8 __attribute__((ext_vector_type(8)));
typedef unsigned short ushort8 __attribute__((ext_vector_type(8)));
typedef float f32x4 __attribute__((ext_vector_type(4)));

// wait until <= N vector-memory ops outstanding (lgkm/exp not waited)
#define WAIT_VM(N) __builtin_amdgcn_s_waitcnt(0xF70 | (N))

__device__ inline unsigned short f2bf(float f) {
    unsigned u = __float_as_uint(f);
    u += 0x7fffu + ((u >> 16) & 1u);
    return (unsigned short)(u >> 16);
}

__device__ inline void gload16(const void* g, void* l) {
    __builtin_amdgcn_global_load_lds(
        (const __attribute__((address_space(1))) unsigned int*)g,
        (__attribute__((address_space(3))) unsigned int*)l, 16, 0, 0);
}

// ---------------- transpose + fp32->bf16 convert: in[K][N] -> out[N][K] ----------------
__global__ void transpose_convert(const float* __restrict__ in, unsigned short* __restrict__ out,
                                  int K, int N) {
    __shared__ float tile[32][33];
    const int n0 = blockIdx.x * 32, k0 = blockIdx.y * 32;
    const int tx = threadIdx.x, ty = threadIdx.y;  // 32 x 8
    for (int r = 0; r < 32; r += 8)
        tile[ty + r][tx] = in[(size_t)(k0 + ty + r) * N + n0 + tx];
    __syncthreads();
    for (int r = 0; r < 32; r += 8)
        out[(size_t)(n0 + ty + r) * K + k0 + tx] = f2bf(tile[tx][ty + r]);
}

// ---------------- V transpose: fp32 qkv-fused row -> bf16 (NKVH, D, S) ----------------
__global__ void transpose_v(const float* __restrict__ qkvf, unsigned short* __restrict__ vbt) {
    __shared__ float tile[32][33];
    const int s0 = blockIdx.x * 32, d0 = blockIdx.y * 32, hv = blockIdx.z;
    const int tx = threadIdx.x, ty = threadIdx.y;  // 32 x 8
    for (int r = 0; r < 32; r += 8)
        tile[ty + r][tx] = qkvf[(size_t)(s0 + ty + r) * QKVN + 5120 + hv * DHEAD + d0 + tx];
    __syncthreads();
    for (int r = 0; r < 32; r += 8)
        vbt[((size_t)hv * DHEAD + d0 + ty + r) * SEQ + s0 + tx] = f2bf(tile[tx][ty + r]);
}

// ---------------- LayerNorm: fp32 (S,H) -> bf16 (S,H) ----------------
__global__ __launch_bounds__(256) void layernorm_kernel(
    const float* __restrict__ hs, const float* __restrict__ w, const float* __restrict__ b,
    unsigned short* __restrict__ xb) {
    const int s = blockIdx.x;
    const float* row = hs + (size_t)s * HDIM;
    const int t = threadIdx.x;
    float vals[16];
    float sum = 0.f, sq = 0.f;
    for (int j = 0; j < 16; j++) {
        float v = row[j * 256 + t];
        vals[j] = v; sum += v; sq += v * v;
    }
    for (int off = 1; off < 64; off <<= 1) {
        sum += __shfl_xor(sum, off);
        sq  += __shfl_xor(sq, off);
    }
    __shared__ float ps[4], pq[4];
    if ((t & 63) == 0) { ps[t >> 6] = sum; pq[t >> 6] = sq; }
    __syncthreads();
    sum = ps[0] + ps[1] + ps[2] + ps[3];
    sq  = pq[0] + pq[1] + pq[2] + pq[3];
    const float mu = sum * (1.0f / HDIM);
    const float var = sq * (1.0f / HDIM) - mu * mu;
    const float rs = rsqrtf(var + 1e-5f);
    for (int j = 0; j < 16; j++) {
        int i = j * 256 + t;
        xb[(size_t)s * HDIM + i] = f2bf((vals[j] - mu) * rs * w[i] + b[i]);
    }
}

// ---------------- 8-phase pipelined GEMM: C = A[M,K] * Bt[N,K]^T (bf16 in, fp32 out) ----
// BM=BN=256, BK=64, 512 thr = 8 waves (2M x 4N), wave tile 128x64.
// LDS: 2 buffers x 2 kh-quadrants x [256][32] per matrix = 128 KB.
// 4 phases per K-tile: {ds_read quadrant frags | stage 1 quadrant of t+1 | setprio MFMA}.
// Gates every 2 phases: WAIT_VM(4)+s_barrier (counted, never drained mid-loop).
// r7 lesson: extra per-phase barrier pairs (PHASE_SYNC) serialize ds_read vs MFMA -> removed.
// 2D-chunked XCD mapping (r7 win: FETCH 204->90MB): XCD x owns a bx slab across all by.
__global__ __launch_bounds__(512, 2) void gemm8p(
    const unsigned short* __restrict__ A, const unsigned short* __restrict__ Bt,
    float* __restrict__ C, int N, int lda, int Keff, int nbx,
    int gridInner, int ksliceElems, long long cSliceStride) {
    __shared__ __align__(16) unsigned short Abuf[2 * 2 * 256 * 32];  // 64 KB
    __shared__ __align__(16) unsigned short Bbuf[2 * 2 * 256 * 32];  // 64 KB

    const int slice = blockIdx.x / gridInner;
    const int inner = blockIdx.x % gridInner;
    // 2D-chunked XCD mapping (requires nbx % 8 == 0, gridInner = nbx * nby)
    const int cbx = nbx >> 3;
    const int xcd = inner & 7, k = inner >> 3;
    const int bx = xcd * cbx + (k % cbx);
    const int by = k / cbx;
    const int row0 = by * 256, col0 = bx * 256;
    A  += (size_t)slice * ksliceElems;
    Bt += (size_t)slice * ksliceElems;
    C  += (size_t)slice * cSliceStride;

    const int t = threadIdx.x, lane = t & 63, w = t >> 6;
    const int wr = w >> 2, wc = w & 3;          // 2M x 4N wave grid
    const int r16 = lane & 15, kq = lane >> 4;

    // staging: thread t covers rows srow and 128+srow, chunk (t&3) pre-swizzled.
    const int srow = t >> 2;
    const int scsw = (t & 3) ^ ((srow >> 1) & 3);
    const unsigned short* aStage = A  + (size_t)(row0 + srow) * lda + scsw * 8;
    const unsigned short* bStage = Bt + (size_t)(col0 + srow) * lda + scsw * 8;
    const size_t half = 128 * (size_t)lda;
    const int wdst = w * 512;  // wave-uniform LDS dest base (elements)

    const int NT = Keff / 64;

#define STAGE(p0, ldsbuf, bufidx, kh, kt) do {                                  \
        const unsigned short* _g = (p0) + (size_t)(kt) * 64 + (kh) * 32;        \
        gload16(_g,        &ldsbuf[((bufidx) * 2 + (kh)) * 8192 + wdst]);       \
        gload16(_g + half, &ldsbuf[((bufidx) * 2 + (kh)) * 8192 + 4096 + wdst]);\
    } while (0)

#define LDA4(dst, bufidx, kh, ih) {                                             \
        _Pragma("unroll") for (int i = 0; i < 4; i++) {                         \
            int arow = wr * 128 + (ih) * 64 + i * 16 + r16;                     \
            dst[i] = *(const bf16x8*)&Abuf[((bufidx) * 2 + (kh)) * 8192 +       \
                     arow * 32 + (kq ^ ((arow >> 1) & 3)) * 8];                 \
        } }

#define LDB4(dst, bufidx, kh) {                                                 \
        _Pragma("unroll") for (int j = 0; j < 4; j++) {                         \
            int brow = wc * 64 + j * 16 + r16;                                  \
            dst[j] = *(const bf16x8*)&Bbuf[((bufidx) * 2 + (kh)) * 8192 +       \
                     brow * 32 + (kq ^ ((brow >> 1) & 3)) * 8];                 \
        } }

#define MM16(ih, av, bv) {                                                      \
        __builtin_amdgcn_s_setprio(1);                                          \
        _Pragma("unroll") for (int i = 0; i < 4; i++)                           \
            _Pragma("unroll") for (int j = 0; j < 4; j++)                       \
                acc[(ih) * 4 + i][j] = __builtin_amdgcn_mfma_f32_16x16x32_bf16( \
                    av[i], bv[j], acc[(ih) * 4 + i][j], 0, 0, 0);               \
        __builtin_amdgcn_s_setprio(0); }

    // prologue: stage all 4 quadrants of K-tile 0 (issue order = ledger order)
    STAGE(aStage, Abuf, 0, 0, 0);
    STAGE(bStage, Bbuf, 0, 0, 0);
    STAGE(aStage, Abuf, 0, 1, 0);
    STAGE(bStage, Bbuf, 0, 1, 0);
    WAIT_VM(4);  // A-kh0, B-kh0 landed; kh1 quadrants in flight
    __builtin_amdgcn_s_barrier();

    f32x4 acc[8][4] = {};
    for (int kt = 0; kt < NT; ++kt) {
        const int cur = kt & 1, nxt = cur ^ 1;
        const bool nl = (kt + 1 < NT);
        bf16x8 a0[4], a1[4], bv[4];
        // ph0: quadrant (ih0, kh0); stage A-kh0(t+1)
        LDA4(a0, cur, 0, 0);
        LDB4(bv, cur, 0);
        if (nl) STAGE(aStage, Abuf, nxt, 0, kt + 1);
        MM16(0, a0, bv);
        // ph1: (ih1, kh0), B reused; stage B-kh0(t+1); mid vmcnt gate
        LDA4(a1, cur, 0, 1);
        if (nl) STAGE(bStage, Bbuf, nxt, 0, kt + 1);
        MM16(1, a1, bv);
        if (nl) WAIT_VM(4); else WAIT_VM(0);  // A-kh1,B-kh1 of THIS tile landed
        __builtin_amdgcn_s_barrier();
        // ph2: (ih0, kh1); stage A-kh1(t+1)
        LDA4(a0, cur, 1, 0);
        LDB4(bv, cur, 1);
        if (nl) STAGE(aStage, Abuf, nxt, 1, kt + 1);
        MM16(0, a0, bv);
        // ph3: (ih1, kh1); stage B-kh1(t+1); boundary vmcnt gate
        LDA4(a1, cur, 1, 1);
        if (nl) STAGE(bStage, Bbuf, nxt, 1, kt + 1);
        MM16(1, a1, bv);
        if (nl) {
            WAIT_VM(4);  // A-kh0,B-kh0 of NEXT tile landed; its kh1 in flight
            __builtin_amdgcn_s_barrier();
        }
    }

    #pragma unroll
    for (int i = 0; i < 8; i++)
        #pragma unroll
        for (int j = 0; j < 4; j++)
            #pragma unroll
            for (int r = 0; r < 4; r++) {
                int row = row0 + wr * 128 + i * 16 + kq * 4 + r;
                int col = col0 + wc * 64 + j * 16 + r16;
                C[(size_t)row * N + col] = acc[i][j][r];
            }
#undef STAGE
#undef LDA4
#undef LDB4
#undef MM16
}

// ---------------- split-K reduce: out = a + b ----------------
__global__ __launch_bounds__(256) void reduce_add(const float* __restrict__ a,
                                                  const float* __restrict__ b,
                                                  float* __restrict__ o, int n) {
    int i = (blockIdx.x * 256 + threadIdx.x) * 4;
    const int stride = gridDim.x * 256 * 4;
    for (; i < n; i += stride) {
        f32x4 x = *(const f32x4*)&a[i];
        f32x4 y = *(const f32x4*)&b[i];
        x += y;
        *(f32x4*)&o[i] = x;
    }
}

// ---------------- RoPE + convert to head-major bf16 (reads fused qkv fp32) ----------------
__global__ void rope_convert(const float* __restrict__ qkvf,
                             unsigned short* __restrict__ qb, unsigned short* __restrict__ kb) {
    const int s = blockIdx.x;
    const int head = blockIdx.y;
    const int d = threadIdx.x;  // 0..63
    const float SCALE = 0.08838834764831845f;  // 1/sqrt(128)
    const float NLOG = -0.14391156831212787f;  // -ln(10000)/64
    float f = (float)s * __expf((float)d * NLOG);
    float sn, c;
    __sincosf(f, &sn, &c);
    if (head < NQH) {
        const float* src = qkvf + (size_t)s * QKVN + head * DHEAD;
        float x1 = src[d], x2 = src[d + 64];
        unsigned short* dst = qb + ((size_t)head * SEQ + s) * DHEAD;
        dst[d]      = f2bf((x1 * c - x2 * sn) * SCALE);
        dst[d + 64] = f2bf((x2 * c + x1 * sn) * SCALE);
    } else {
        const int hk = head - NQH;
        const float* src = qkvf + (size_t)s * QKVN + 4096 + hk * DHEAD;
        float x1 = src[d], x2 = src[d + 64];
        unsigned short* dst = kb + ((size_t)hk * SEQ + s) * DHEAD;
        dst[d]      = f2bf(x1 * c - x2 * sn);
        dst[d + 64] = f2bf(x2 * c + x1 * sn);
    }
}

// ---------------- Flash attention, qb-paired for causal load balance ----------------
// Block = (head h, pair p): q-tiles qbS=p and qbL=31-p -> every block runs exactly
// qbL+1 KV iters; shared kb prefix reuses each staged K/V tile for both tiles
// (2x MFMA per stage). Grid 512 = 2 blocks/CU, no causal tail.
// T14 async-STAGE (reg-staged K/V for kb+1 issued before compute) + T13 defer-max.
__global__ __launch_bounds__(256) void attention_kernel(
    const unsigned short* __restrict__ Q, const unsigned short* __restrict__ K,
    const unsigned short* __restrict__ Vt, unsigned short* __restrict__ O) {
    __shared__ __align__(16) unsigned short Ks[64 * 128];    // [kcol][d], swizzled
    __shared__ __align__(16) unsigned short Vs[128 * 64];    // [d][k], swizzled
    __shared__ __align__(16) unsigned short Pl[4][16 * 64];  // per-wave [qr][k], swizzled
    const int h = blockIdx.x >> 4;        // 0..31
    const int p = blockIdx.x & 15;        // 0..15
    const int qbS = p, qbL = (SEQ / 64 - 1) - p;
    const int t = threadIdx.x, lane = t & 63, wave = t >> 6;
    const int r16 = lane & 15, kq = lane >> 4;
    const int q0S = qbS * 64 + wave * 16;
    const int q0L = qbL * 64 + wave * 16;
    const int hkv = h >> 2;

    bf16x8 qfS[4], qfL[4];
    {
        const unsigned short* qrS = Q + ((size_t)h * SEQ + q0S + r16) * DHEAD;
        const unsigned short* qrL = Q + ((size_t)h * SEQ + q0L + r16) * DHEAD;
        for (int c = 0; c < 4; c++) {
            qfS[c] = *(const bf16x8*)&qrS[c * 32 + kq * 8];
            qfL[c] = *(const bf16x8*)&qrL[c * 32 + kq * 8];
        }
    }

    f32x4 accS[8] = {}, accL[8] = {};
    float mS[4], lS[4], mL[4], lL[4];
    for (int r = 0; r < 4; r++) { mS[r] = -1e30f; lS[r] = 0.f; mL[r] = -1e30f; lL[r] = 0.f; }

    const unsigned short* Kg = K + (size_t)hkv * SEQ * DHEAD;
    const unsigned short* Vg = Vt + (size_t)hkv * DHEAD * SEQ;
    unsigned short* pw = &Pl[wave][0];

    const int krow = t >> 4, kch = t & 15;   // K staging: 4 rows/iter via +16
    const int vrow = t >> 3, vch = t & 7;    // V staging: 32 d-rows/iter via +32

    ushort8 kreg[4], vreg[4];
    #pragma unroll
    for (int pp = 0; pp < 4; pp++) {
        kreg[pp] = *(const ushort8*)&Kg[(size_t)(pp * 16 + krow) * DHEAD + kch * 8];
        vreg[pp] = *(const ushort8*)&Vg[(size_t)(pp * 32 + vrow) * SEQ + vch * 8];
    }

    // one (QK -> softmax -> PV) step for a q-tile's state against the staged 64-col tile
    auto process = [&](const bf16x8* qf, f32x4* acc, float* m_r, float* l_r,
                       int q0, bool diag, int kb) {
        f32x4 sf[4];
        for (int ct = 0; ct < 4; ct++) {
            f32x4 s4 = {};
            int row = ct * 16 + r16;
            for (int c = 0; c < 4; c++) {
                int ch = (c * 4 + kq) ^ (row & 7);
                bf16x8 kf2 = *(const bf16x8*)&Ks[row * 128 + ch * 8];
                s4 = __builtin_amdgcn_mfma_f32_16x16x32_bf16(qf[c], kf2, s4, 0, 0, 0);
            }
            sf[ct] = s4;
        }
        if (diag) {
            for (int r = 0; r < 4; r++) {
                int qg = q0 + kq * 4 + r;
                for (int ct = 0; ct < 4; ct++) {
                    int col = kb * 64 + ct * 16 + r16;
                    if (col > qg) sf[ct][r] = -1e30f;
                }
            }
        }
        float pmax[4];
        for (int r = 0; r < 4; r++) {
            float mx = fmaxf(fmaxf(sf[0][r], sf[1][r]), fmaxf(sf[2][r], sf[3][r]));
            for (int off = 1; off < 16; off <<= 1) mx = fmaxf(mx, __shfl_xor(mx, off, 16));
            pmax[r] = mx;
        }
        bool grow = (pmax[0] > m_r[0] + 8.f) | (pmax[1] > m_r[1] + 8.f) |
                    (pmax[2] > m_r[2] + 8.f) | (pmax[3] > m_r[3] + 8.f);
        if (__any(grow)) {
            for (int r = 0; r < 4; r++) {
                float mn = fmaxf(m_r[r], pmax[r]);
                float sc = __expf(m_r[r] - mn);
                l_r[r] *= sc;
                for (int nt = 0; nt < 8; nt++) acc[nt][r] *= sc;
                m_r[r] = mn;
            }
        }
        for (int r = 0; r < 4; r++) {
            float sum = 0.f;
            for (int ct = 0; ct < 4; ct++) {
                float pv = __expf(sf[ct][r] - m_r[r]);
                sf[ct][r] = pv; sum += pv;
            }
            for (int off = 1; off < 16; off <<= 1) sum += __shfl_xor(sum, off, 16);
            l_r[r] += sum;
        }
        for (int ct = 0; ct < 4; ct++)
            for (int r = 0; r < 4; r++) {
                int prow = kq * 4 + r, col = ct * 16 + r16;
                int ch = (col >> 3) ^ (prow & 7);
                pw[prow * 64 + ch * 8 + (col & 7)] = f2bf(sf[ct][r]);
            }
        for (int k32 = 0; k32 < 2; k32++) {
            int pch = (k32 * 4 + kq) ^ (r16 & 7);
            bf16x8 pf = *(const bf16x8*)&pw[r16 * 64 + pch * 8];
            for (int nt = 0; nt < 8; nt++) {
                int vr2 = nt * 16 + r16;
                int vc2 = (k32 * 4 + kq) ^ (vr2 & 7);
                bf16x8 vfr = *(const bf16x8*)&Vs[vr2 * 64 + vc2 * 8];
                acc[nt] = __builtin_amdgcn_mfma_f32_16x16x32_bf16(pf, vfr, acc[nt], 0, 0, 0);
            }
        }
    };

    for (int kb = 0; kb <= qbL; ++kb) {
        __syncthreads();
        #pragma unroll
        for (int pp = 0; pp < 4; pp++) {
            int row = pp * 16 + krow;
            *(ushort8*)&Ks[row * 128 + ((kch ^ (row & 7)) * 8)] = kreg[pp];
            int vr = pp * 32 + vrow;
            *(ushort8*)&Vs[vr * 64 + ((vch ^ (vr & 7)) * 8)] = vreg[pp];
        }
        if (kb < qbL) {
            #pragma unroll
            for (int pp = 0; pp < 4; pp++) {
                kreg[pp] = *(const ushort8*)&Kg[(size_t)((kb + 1) * 64 + pp * 16 + krow) * DHEAD + kch * 8];
                vreg[pp] = *(const ushort8*)&Vg[(size_t)(pp * 32 + vrow) * SEQ + (kb + 1) * 64 + vch * 8];
            }
        }
        __syncthreads();
        process(qfL, accL, mL, lL, q0L, kb == qbL, kb);
        if (kb <= qbS) process(qfS, accS, mS, lS, q0S, kb == qbS, kb);
    }

    float invS[4], invL[4];
    for (int r = 0; r < 4; r++) { invS[r] = 1.0f / lS[r]; invL[r] = 1.0f / lL[r]; }
    for (int nt = 0; nt < 8; nt++)
        for (int r = 0; r < 4; r++) {
            O[(size_t)(q0L + kq * 4 + r) * HDIM + h * DHEAD + nt * 16 + r16] =
                f2bf(accL[nt][r] * invL[r]);
            O[(size_t)(q0S + kq * 4 + r) * HDIM + h * DHEAD + nt * 16 + r16] =
                f2bf(accS[nt][r] * invS[r]);
        }
}

extern "C" void kernel_launch(void* const* d_in, const int* in_sizes, int n_in,
                              void* d_out, int out_size, void* d_ws, size_t ws_size,
                              hipStream_t stream) {
    const float* hs  = (const float*)d_in[0];
    const float* lnw = (const float*)d_in[1];
    const float* lnb = (const float*)d_in[2];
    const float* wq  = (const float*)d_in[3];
    const float* wk  = (const float*)d_in[4];
    const float* wv  = (const float*)d_in[5];
    const float* wo  = (const float*)d_in[6];
    float* out = (float*)d_out;

    char* ws = (char*)d_ws;
    size_t off = 0;
    auto alloc = [&](size_t bytes) {
        void* p = ws + off;
        off += (bytes + 255) & ~(size_t)255;
        return p;
    };
    unsigned short* xb   = (unsigned short*)alloc((size_t)SEQ * HDIM * 2);
    // wqT/wkT/wvT contiguous -> fused [6144][4096] B matrix
    unsigned short* wqT  = (unsigned short*)alloc((size_t)HDIM * (NQH * DHEAD) * 2);
    unsigned short* wkT  = (unsigned short*)alloc((size_t)HDIM * (NKVH * DHEAD) * 2);
    unsigned short* wvT  = (unsigned short*)alloc((size_t)HDIM * (NKVH * DHEAD) * 2);
    unsigned short* woT  = (unsigned short*)alloc((size_t)(NQH * DHEAD) * HDIM * 2);
    float* qkvf          = (float*)alloc((size_t)SEQ * QKVN * 4);
    unsigned short* qbuf = (unsigned short*)alloc((size_t)NQH * SEQ * DHEAD * 2);
    unsigned short* kbuf = (unsigned short*)alloc((size_t)NKVH * SEQ * DHEAD * 2);
    unsigned short* vbt  = (unsigned short*)alloc((size_t)NKVH * DHEAD * SEQ * 2);
    unsigned short* attnb = (unsigned short*)qkvf;  // reuse fused-fp32 region after rope/v-transpose
    // split-K partials for O-proj: exactly 64 MiB, overlays xb+wqT+wkT+wvT (dead by then)
    float* cpart = (float*)xb;

    dim3 tb(32, 8);
    transpose_convert<<<dim3(4096 / 32, 4096 / 32), tb, 0, stream>>>(wq, wqT, 4096, 4096);
    transpose_convert<<<dim3(1024 / 32, 4096 / 32), tb, 0, stream>>>(wk, wkT, 4096, 1024);
    transpose_convert<<<dim3(1024 / 32, 4096 / 32), tb, 0, stream>>>(wv, wvT, 4096, 1024);
    transpose_convert<<<dim3(4096 / 32, 4096 / 32), tb, 0, stream>>>(wo, woT, 4096, 4096);

    layernorm_kernel<<<SEQ, 256, 0, stream>>>(hs, lnw, lnb, xb);

    // fused QKV projection: [2048][4096] x [6144][4096]^T -> [2048][6144]
    gemm8p<<<(2048 / 256) * (QKVN / 256), 512, 0, stream>>>(
        xb, wqT, qkvf, QKVN, 4096, 4096, QKVN / 256, (2048 / 256) * (QKVN / 256), 0, 0);

    rope_convert<<<dim3(SEQ, NQH + NKVH), 64, 0, stream>>>(qkvf, qbuf, kbuf);
    transpose_v<<<dim3(SEQ / 32, DHEAD / 32, NKVH), tb, 0, stream>>>(qkvf, vbt);

    // qb-paired attention: grid = 32 heads x 16 pairs
    attention_kernel<<<NQH * 16, 256, 0, stream>>>(qbuf, kbuf, vbt, attnb);

    // O-proj with split-K=2: grid 256 = 2 slices x 128 blocks, K=2048 each
    gemm8p<<<2 * (2048 / 256) * (4096 / 256), 512, 0, stream>>>(
        attnb, woT, cpart, 4096, 4096, 2048, 4096 / 256,
        (2048 / 256) * (4096 / 256), 2048, (long long)2048 * 4096);
    reduce_add<<<2048, 256, 0, stream>>>(cpart, cpart + (size_t)2048 * 4096, out,
                                         2048 * 4096);
}

// Round 10
// 389.227 us; speedup vs baseline: 1.0631x; 1.0631x over previous
//
#include <hip/hip_runtime.h>
#include <hip/hip_bf16.h>

#define HDIM 4096
#define DHEAD 128
#define NQH 32
#define NKVH 8
#define SEQ 2048
#define QKVN 6144  // fused N = 4096 + 1024 + 1024

typedef __bf16 bf16x8 __attribute__((ext_vector_type(8)));
typedef unsigned short ushort8 __attribute__((ext_vector_type(8)));
typedef float f32x4 __attribute__((ext_vector_type(4)));

// wait until <= N vector-memory ops outstanding (lgkm/exp not waited)
#define WAIT_VM(N) __builtin_amdgcn_s_waitcnt(0xF70 | (N))

__device__ inline unsigned short f2bf(float f) {
    unsigned u = __float_as_uint(f);
    u += 0x7fffu + ((u >> 16) & 1u);
    return (unsigned short)(u >> 16);
}

__device__ inline void gload16(const void* g, void* l) {
    __builtin_amdgcn_global_load_lds(
        (const __attribute__((address_space(1))) unsigned int*)g,
        (__attribute__((address_space(3))) unsigned int*)l, 16, 0, 0);
}

// ---------------- transpose + fp32->bf16 convert: in[K][N] -> out[N][K] ----------------
__global__ void transpose_convert(const float* __restrict__ in, unsigned short* __restrict__ out,
                                  int K, int N) {
    __shared__ float tile[32][33];
    const int n0 = blockIdx.x * 32, k0 = blockIdx.y * 32;
    const int tx = threadIdx.x, ty = threadIdx.y;  // 32 x 8
    for (int r = 0; r < 32; r += 8)
        tile[ty + r][tx] = in[(size_t)(k0 + ty + r) * N + n0 + tx];
    __syncthreads();
    for (int r = 0; r < 32; r += 8)
        out[(size_t)(n0 + ty + r) * K + k0 + tx] = f2bf(tile[tx][ty + r]);
}

// ---------------- V transpose: fp32 qkv-fused row -> bf16 (NKVH, D, S) ----------------
__global__ void transpose_v(const float* __restrict__ qkvf, unsigned short* __restrict__ vbt) {
    __shared__ float tile[32][33];
    const int s0 = blockIdx.x * 32, d0 = blockIdx.y * 32, hv = blockIdx.z;
    const int tx = threadIdx.x, ty = threadIdx.y;  // 32 x 8
    for (int r = 0; r < 32; r += 8)
        tile[ty + r][tx] = qkvf[(size_t)(s0 + ty + r) * QKVN + 5120 + hv * DHEAD + d0 + tx];
    __syncthreads();
    for (int r = 0; r < 32; r += 8)
        vbt[((size_t)hv * DHEAD + d0 + ty + r) * SEQ + s0 + tx] = f2bf(tile[tx][ty + r]);
}

// ---------------- LayerNorm: fp32 (S,H) -> bf16 (S,H) ----------------
__global__ __launch_bounds__(256) void layernorm_kernel(
    const float* __restrict__ hs, const float* __restrict__ w, const float* __restrict__ b,
    unsigned short* __restrict__ xb) {
    const int s = blockIdx.x;
    const float* row = hs + (size_t)s * HDIM;
    const int t = threadIdx.x;
    float vals[16];
    float sum = 0.f, sq = 0.f;
    for (int j = 0; j < 16; j++) {
        float v = row[j * 256 + t];
        vals[j] = v; sum += v; sq += v * v;
    }
    for (int off = 1; off < 64; off <<= 1) {
        sum += __shfl_xor(sum, off);
        sq  += __shfl_xor(sq, off);
    }
    __shared__ float ps[4], pq[4];
    if ((t & 63) == 0) { ps[t >> 6] = sum; pq[t >> 6] = sq; }
    __syncthreads();
    sum = ps[0] + ps[1] + ps[2] + ps[3];
    sq  = pq[0] + pq[1] + pq[2] + pq[3];
    const float mu = sum * (1.0f / HDIM);
    const float var = sq * (1.0f / HDIM) - mu * mu;
    const float rs = rsqrtf(var + 1e-5f);
    for (int j = 0; j < 16; j++) {
        int i = j * 256 + t;
        xb[(size_t)s * HDIM + i] = f2bf((vals[j] - mu) * rs * w[i] + b[i]);
    }
}

// ---------------- 8-phase pipelined GEMM: C = A[M,K] * Bt[N,K]^T (bf16 in, fp32 out) ----
// BM=BN=256, BK=64, 512 thr = 8 waves (2M x 4N), wave tile 128x64.
// LDS: 2 buffers x 2 kh-quadrants x [256][32] per matrix = 128 KB.
// 4 phases per K-tile: {ds_read quadrant frags | stage 1 quadrant of t+1 | setprio MFMA}.
// Gates every 2 phases: WAIT_VM(4)+s_barrier (counted, never drained mid-loop).
// r7 lesson: extra per-phase barrier pairs serialize ds_read vs MFMA -> single gate kept.
// 2D-chunked XCD mapping (r7 win: FETCH 204->90MB): XCD x owns a bx slab across all by.
__global__ __launch_bounds__(512, 2) void gemm8p(
    const unsigned short* __restrict__ A, const unsigned short* __restrict__ Bt,
    float* __restrict__ C, int N, int lda, int Keff, int nbx,
    int gridInner, int ksliceElems, long long cSliceStride) {
    __shared__ __align__(16) unsigned short Abuf[2 * 2 * 256 * 32];  // 64 KB
    __shared__ __align__(16) unsigned short Bbuf[2 * 2 * 256 * 32];  // 64 KB

    const int slice = blockIdx.x / gridInner;
    const int inner = blockIdx.x % gridInner;
    // 2D-chunked XCD mapping (requires nbx % 8 == 0, gridInner = nbx * nby)
    const int cbx = nbx >> 3;
    const int xcd = inner & 7, k = inner >> 3;
    const int bx = xcd * cbx + (k % cbx);
    const int by = k / cbx;
    const int row0 = by * 256, col0 = bx * 256;
    A  += (size_t)slice * ksliceElems;
    Bt += (size_t)slice * ksliceElems;
    C  += (size_t)slice * cSliceStride;

    const int t = threadIdx.x, lane = t & 63, w = t >> 6;
    const int wr = w >> 2, wc = w & 3;          // 2M x 4N wave grid
    const int r16 = lane & 15, kq = lane >> 4;

    // staging: thread t covers rows srow and 128+srow, chunk (t&3) pre-swizzled.
    const int srow = t >> 2;
    const int scsw = (t & 3) ^ ((srow >> 1) & 3);
    const unsigned short* aStage = A  + (size_t)(row0 + srow) * lda + scsw * 8;
    const unsigned short* bStage = Bt + (size_t)(col0 + srow) * lda + scsw * 8;
    const size_t half = 128 * (size_t)lda;
    const int wdst = w * 512;  // wave-uniform LDS dest base (elements)

    const int NT = Keff / 64;

#define STAGE(p0, ldsbuf, bufidx, kh, kt) do {                                  \
        const unsigned short* _g = (p0) + (size_t)(kt) * 64 + (kh) * 32;        \
        gload16(_g,        &ldsbuf[((bufidx) * 2 + (kh)) * 8192 + wdst]);       \
        gload16(_g + half, &ldsbuf[((bufidx) * 2 + (kh)) * 8192 + 4096 + wdst]);\
    } while (0)

#define LDA4(dst, bufidx, kh, ih) {                                             \
        _Pragma("unroll") for (int i = 0; i < 4; i++) {                         \
            int arow = wr * 128 + (ih) * 64 + i * 16 + r16;                     \
            dst[i] = *(const bf16x8*)&Abuf[((bufidx) * 2 + (kh)) * 8192 +       \
                     arow * 32 + (kq ^ ((arow >> 1) & 3)) * 8];                 \
        } }

#define LDB4(dst, bufidx, kh) {                                                 \
        _Pragma("unroll") for (int j = 0; j < 4; j++) {                         \
            int brow = wc * 64 + j * 16 + r16;                                  \
            dst[j] = *(const bf16x8*)&Bbuf[((bufidx) * 2 + (kh)) * 8192 +       \
                     brow * 32 + (kq ^ ((brow >> 1) & 3)) * 8];                 \
        } }

#define MM16(ih, av, bv) {                                                      \
        __builtin_amdgcn_s_setprio(1);                                          \
        _Pragma("unroll") for (int i = 0; i < 4; i++)                           \
            _Pragma("unroll") for (int j = 0; j < 4; j++)                       \
                acc[(ih) * 4 + i][j] = __builtin_amdgcn_mfma_f32_16x16x32_bf16( \
                    av[i], bv[j], acc[(ih) * 4 + i][j], 0, 0, 0);               \
        __builtin_amdgcn_s_setprio(0); }

    // prologue: stage all 4 quadrants of K-tile 0 (issue order = ledger order)
    STAGE(aStage, Abuf, 0, 0, 0);
    STAGE(bStage, Bbuf, 0, 0, 0);
    STAGE(aStage, Abuf, 0, 1, 0);
    STAGE(bStage, Bbuf, 0, 1, 0);
    WAIT_VM(4);  // A-kh0, B-kh0 landed; kh1 quadrants in flight
    __builtin_amdgcn_s_barrier();

    f32x4 acc[8][4] = {};
    for (int kt = 0; kt < NT; ++kt) {
        const int cur = kt & 1, nxt = cur ^ 1;
        const bool nl = (kt + 1 < NT);
        bf16x8 a0[4], a1[4], bv[4];
        // ph0: quadrant (ih0, kh0); stage A-kh0(t+1)
        LDA4(a0, cur, 0, 0);
        LDB4(bv, cur, 0);
        if (nl) STAGE(aStage, Abuf, nxt, 0, kt + 1);
        MM16(0, a0, bv);
        // ph1: (ih1, kh0), B reused; stage B-kh0(t+1); mid vmcnt gate
        LDA4(a1, cur, 0, 1);
        if (nl) STAGE(bStage, Bbuf, nxt, 0, kt + 1);
        MM16(1, a1, bv);
        if (nl) WAIT_VM(4); else WAIT_VM(0);  // A-kh1,B-kh1 of THIS tile landed
        __builtin_amdgcn_s_barrier();
        // ph2: (ih0, kh1); stage A-kh1(t+1)
        LDA4(a0, cur, 1, 0);
        LDB4(bv, cur, 1);
        if (nl) STAGE(aStage, Abuf, nxt, 1, kt + 1);
        MM16(0, a0, bv);
        // ph3: (ih1, kh1); stage B-kh1(t+1); boundary vmcnt gate
        LDA4(a1, cur, 1, 1);
        if (nl) STAGE(bStage, Bbuf, nxt, 1, kt + 1);
        MM16(1, a1, bv);
        if (nl) {
            WAIT_VM(4);  // A-kh0,B-kh0 of NEXT tile landed; its kh1 in flight
            __builtin_amdgcn_s_barrier();
        }
    }

    #pragma unroll
    for (int i = 0; i < 8; i++)
        #pragma unroll
        for (int j = 0; j < 4; j++)
            #pragma unroll
            for (int r = 0; r < 4; r++) {
                int row = row0 + wr * 128 + i * 16 + kq * 4 + r;
                int col = col0 + wc * 64 + j * 16 + r16;
                C[(size_t)row * N + col] = acc[i][j][r];
            }
#undef STAGE
#undef LDA4
#undef LDB4
#undef MM16
}

// ---------------- split-K reduce: out = a + b ----------------
__global__ __launch_bounds__(256) void reduce_add(const float* __restrict__ a,
                                                  const float* __restrict__ b,
                                                  float* __restrict__ o, int n) {
    int i = (blockIdx.x * 256 + threadIdx.x) * 4;
    const int stride = gridDim.x * 256 * 4;
    for (; i < n; i += stride) {
        f32x4 x = *(const f32x4*)&a[i];
        f32x4 y = *(const f32x4*)&b[i];
        x += y;
        *(f32x4*)&o[i] = x;
    }
}

// ---------------- RoPE + convert to head-major bf16 (reads fused qkv fp32) ----------------
__global__ void rope_convert(const float* __restrict__ qkvf,
                             unsigned short* __restrict__ qb, unsigned short* __restrict__ kb) {
    const int s = blockIdx.x;
    const int head = blockIdx.y;
    const int d = threadIdx.x;  // 0..63
    const float SCALE = 0.08838834764831845f;  // 1/sqrt(128)
    const float NLOG = -0.14391156831212787f;  // -ln(10000)/64
    float f = (float)s * __expf((float)d * NLOG);
    float sn, c;
    __sincosf(f, &sn, &c);
    if (head < NQH) {
        const float* src = qkvf + (size_t)s * QKVN + head * DHEAD;
        float x1 = src[d], x2 = src[d + 64];
        unsigned short* dst = qb + ((size_t)head * SEQ + s) * DHEAD;
        dst[d]      = f2bf((x1 * c - x2 * sn) * SCALE);
        dst[d + 64] = f2bf((x2 * c + x1 * sn) * SCALE);
    } else {
        const int hk = head - NQH;
        const float* src = qkvf + (size_t)s * QKVN + 4096 + hk * DHEAD;
        float x1 = src[d], x2 = src[d + 64];
        unsigned short* dst = kb + ((size_t)hk * SEQ + s) * DHEAD;
        dst[d]      = f2bf(x1 * c - x2 * sn);
        dst[d + 64] = f2bf(x2 * c + x1 * sn);
    }
}

// ---------------- Flash attention: 8-wave blocks, 128 q-rows each ----------------
// Block = (head h, 128-row q-slab p). 8 waves x 16 q-rows; single per-wave state
// (r9 lesson: dual-state pairing -> 184 VGPR, 10% occupancy). Each staged 64-col
// K/V tile feeds 8 waves (2x amortization vs 4-wave). Waves past their diagonal
// skip compute via wave-uniform continue (barrier counts stay matched).
// T14 async reg-staging (2 x ushort8 per matrix) + T13 defer-max.
__global__ __launch_bounds__(512, 4) void attention_kernel(
    const unsigned short* __restrict__ Q, const unsigned short* __restrict__ K,
    const unsigned short* __restrict__ Vt, unsigned short* __restrict__ O) {
    __shared__ __align__(16) unsigned short Ks[64 * 128];    // [kcol][d], swizzled
    __shared__ __align__(16) unsigned short Vs[128 * 64];    // [d][k], swizzled
    __shared__ __align__(16) unsigned short Pl[8][16 * 64];  // per-wave [qr][k], swizzled
    const int h = blockIdx.x & 31;
    const int p = 15 - (blockIdx.x >> 5);   // LPT: largest slabs first
    const int t = threadIdx.x, lane = t & 63, wave = t >> 6;
    const int r16 = lane & 15, kq = lane >> 4;
    const int q0 = p * 128 + wave * 16;
    const int kbw = q0 >> 6;                // this wave's diagonal kb
    const int kbmax = 2 * p + 1;            // block's last kb
    const int hkv = h >> 2;

    bf16x8 qfrag[4];
    const unsigned short* qrow = Q + ((size_t)h * SEQ + q0 + r16) * DHEAD;
    for (int c = 0; c < 4; c++) qfrag[c] = *(const bf16x8*)&qrow[c * 32 + kq * 8];

    f32x4 acc[8] = {};
    float m_r[4], l_r[4];
    for (int r = 0; r < 4; r++) { m_r[r] = -1e30f; l_r[r] = 0.f; }

    const unsigned short* Kg = K + (size_t)hkv * SEQ * DHEAD;
    const unsigned short* Vg = Vt + (size_t)hkv * DHEAD * SEQ;
    unsigned short* pw = &Pl[wave][0];

    // staging tasks: K = 64 rows x 16 chunks, V = 128 rows x 8 chunks; 2 per thread
    const int krow = t >> 4, kch = t & 15;   // K rows: pp*32 + krow
    const int vrow = t >> 3, vch = t & 7;    // V rows: pp*64 + vrow

    ushort8 kreg[2], vreg[2];
    #pragma unroll
    for (int pp = 0; pp < 2; pp++) {
        kreg[pp] = *(const ushort8*)&Kg[(size_t)(pp * 32 + krow) * DHEAD + kch * 8];
        vreg[pp] = *(const ushort8*)&Vg[(size_t)(pp * 64 + vrow) * SEQ + vch * 8];
    }

    for (int kb = 0; kb <= kbmax; ++kb) {
        __syncthreads();
        #pragma unroll
        for (int pp = 0; pp < 2; pp++) {
            int row = pp * 32 + krow;
            *(ushort8*)&Ks[row * 128 + ((kch ^ (row & 7)) * 8)] = kreg[pp];
            int vr = pp * 64 + vrow;
            *(ushort8*)&Vs[vr * 64 + ((vch ^ (vr & 7)) * 8)] = vreg[pp];
        }
        if (kb < kbmax) {
            #pragma unroll
            for (int pp = 0; pp < 2; pp++) {
                kreg[pp] = *(const ushort8*)&Kg[(size_t)((kb + 1) * 64 + pp * 32 + krow) * DHEAD + kch * 8];
                vreg[pp] = *(const ushort8*)&Vg[(size_t)(pp * 64 + vrow) * SEQ + (kb + 1) * 64 + vch * 8];
            }
        }
        __syncthreads();
        if (kb > kbw) continue;  // fully-masked for this wave; barriers stay matched
        f32x4 sf[4];
        for (int ct = 0; ct < 4; ct++) {
            f32x4 s4 = {};
            int row = ct * 16 + r16;
            for (int c = 0; c < 4; c++) {
                int ch = (c * 4 + kq) ^ (row & 7);
                bf16x8 kf2 = *(const bf16x8*)&Ks[row * 128 + ch * 8];
                s4 = __builtin_amdgcn_mfma_f32_16x16x32_bf16(qfrag[c], kf2, s4, 0, 0, 0);
            }
            sf[ct] = s4;
        }
        if (kb == kbw) {
            for (int r = 0; r < 4; r++) {
                int qg = q0 + kq * 4 + r;
                for (int ct = 0; ct < 4; ct++) {
                    int col = kb * 64 + ct * 16 + r16;
                    if (col > qg) sf[ct][r] = -1e30f;
                }
            }
        }
        // online softmax with defer-max (T13)
        float pmax[4];
        for (int r = 0; r < 4; r++) {
            float mx = fmaxf(fmaxf(sf[0][r], sf[1][r]), fmaxf(sf[2][r], sf[3][r]));
            for (int off = 1; off < 16; off <<= 1) mx = fmaxf(mx, __shfl_xor(mx, off, 16));
            pmax[r] = mx;
        }
        bool grow = (pmax[0] > m_r[0] + 8.f) | (pmax[1] > m_r[1] + 8.f) |
                    (pmax[2] > m_r[2] + 8.f) | (pmax[3] > m_r[3] + 8.f);
        if (__any(grow)) {
            for (int r = 0; r < 4; r++) {
                float mn = fmaxf(m_r[r], pmax[r]);
                float sc = __expf(m_r[r] - mn);
                l_r[r] *= sc;
                for (int nt = 0; nt < 8; nt++) acc[nt][r] *= sc;
                m_r[r] = mn;
            }
        }
        for (int r = 0; r < 4; r++) {
            float sum = 0.f;
            for (int ct = 0; ct < 4; ct++) {
                float pv = __expf(sf[ct][r] - m_r[r]);
                sf[ct][r] = pv; sum += pv;
            }
            for (int off = 1; off < 16; off <<= 1) sum += __shfl_xor(sum, off, 16);
            l_r[r] += sum;
        }
        for (int ct = 0; ct < 4; ct++)
            for (int r = 0; r < 4; r++) {
                int prow = kq * 4 + r, col = ct * 16 + r16;
                int ch = (col >> 3) ^ (prow & 7);
                pw[prow * 64 + ch * 8 + (col & 7)] = f2bf(sf[ct][r]);
            }
        for (int k32 = 0; k32 < 2; k32++) {
            int pch = (k32 * 4 + kq) ^ (r16 & 7);
            bf16x8 pf = *(const bf16x8*)&pw[r16 * 64 + pch * 8];
            for (int nt = 0; nt < 8; nt++) {
                int vr2 = nt * 16 + r16;
                int vc2 = (k32 * 4 + kq) ^ (vr2 & 7);
                bf16x8 vfr = *(const bf16x8*)&Vs[vr2 * 64 + vc2 * 8];
                acc[nt] = __builtin_amdgcn_mfma_f32_16x16x32_bf16(pf, vfr, acc[nt], 0, 0, 0);
            }
        }
    }
    float invl[4];
    for (int r = 0; r < 4; r++) invl[r] = 1.0f / l_r[r];
    for (int nt = 0; nt < 8; nt++)
        for (int r = 0; r < 4; r++)
            O[(size_t)(q0 + kq * 4 + r) * HDIM + h * DHEAD + nt * 16 + r16] =
                f2bf(acc[nt][r] * invl[r]);
}

extern "C" void kernel_launch(void* const* d_in, const int* in_sizes, int n_in,
                              void* d_out, int out_size, void* d_ws, size_t ws_size,
                              hipStream_t stream) {
    const float* hs  = (const float*)d_in[0];
    const float* lnw = (const float*)d_in[1];
    const float* lnb = (const float*)d_in[2];
    const float* wq  = (const float*)d_in[3];
    const float* wk  = (const float*)d_in[4];
    const float* wv  = (const float*)d_in[5];
    const float* wo  = (const float*)d_in[6];
    float* out = (float*)d_out;

    char* ws = (char*)d_ws;
    size_t off = 0;
    auto alloc = [&](size_t bytes) {
        void* p = ws + off;
        off += (bytes + 255) & ~(size_t)255;
        return p;
    };
    unsigned short* xb   = (unsigned short*)alloc((size_t)SEQ * HDIM * 2);
    // wqT/wkT/wvT contiguous -> fused [6144][4096] B matrix
    unsigned short* wqT  = (unsigned short*)alloc((size_t)HDIM * (NQH * DHEAD) * 2);
    unsigned short* wkT  = (unsigned short*)alloc((size_t)HDIM * (NKVH * DHEAD) * 2);
    unsigned short* wvT  = (unsigned short*)alloc((size_t)HDIM * (NKVH * DHEAD) * 2);
    unsigned short* woT  = (unsigned short*)alloc((size_t)(NQH * DHEAD) * HDIM * 2);
    float* qkvf          = (float*)alloc((size_t)SEQ * QKVN * 4);
    unsigned short* qbuf = (unsigned short*)alloc((size_t)NQH * SEQ * DHEAD * 2);
    unsigned short* kbuf = (unsigned short*)alloc((size_t)NKVH * SEQ * DHEAD * 2);
    unsigned short* vbt  = (unsigned short*)alloc((size_t)NKVH * DHEAD * SEQ * 2);
    unsigned short* attnb = (unsigned short*)qkvf;  // reuse fused-fp32 region after rope/v-transpose
    // split-K partials for O-proj: exactly 64 MiB, overlays xb+wqT+wkT+wvT (dead by then)
    float* cpart = (float*)xb;

    dim3 tb(32, 8);
    transpose_convert<<<dim3(4096 / 32, 4096 / 32), tb, 0, stream>>>(wq, wqT, 4096, 4096);
    transpose_convert<<<dim3(1024 / 32, 4096 / 32), tb, 0, stream>>>(wk, wkT, 4096, 1024);
    transpose_convert<<<dim3(1024 / 32, 4096 / 32), tb, 0, stream>>>(wv, wvT, 4096, 1024);
    transpose_convert<<<dim3(4096 / 32, 4096 / 32), tb, 0, stream>>>(wo, woT, 4096, 4096);

    layernorm_kernel<<<SEQ, 256, 0, stream>>>(hs, lnw, lnb, xb);

    // fused QKV projection: [2048][4096] x [6144][4096]^T -> [2048][6144]
    gemm8p<<<(2048 / 256) * (QKVN / 256), 512, 0, stream>>>(
        xb, wqT, qkvf, QKVN, 4096, 4096, QKVN / 256, (2048 / 256) * (QKVN / 256), 0, 0);

    rope_convert<<<dim3(SEQ, NQH + NKVH), 64, 0, stream>>>(qkvf, qbuf, kbuf);
    transpose_v<<<dim3(SEQ / 32, DHEAD / 32, NKVH), tb, 0, stream>>>(qkvf, vbt);

    // 8-wave attention: grid = 32 heads x 16 q-slabs (128 rows each)
    attention_kernel<<<NQH * 16, 512, 0, stream>>>(qbuf, kbuf, vbt, attnb);

    // O-proj with split-K=2: grid 256 = 2 slices x 128 blocks, K=2048 each
    gemm8p<<<2 * (2048 / 256) * (4096 / 256), 512, 0, stream>>>(
        attnb, woT, cpart, 4096, 4096, 2048, 4096 / 256,
        (2048 / 256) * (4096 / 256), 2048, (long long)2048 * 4096);
    reduce_add<<<2048, 256, 0, stream>>>(cpart, cpart + (size_t)2048 * 4096, out,
                                         2048 * 4096);
}

// Round 11
// 340.187 us; speedup vs baseline: 1.2164x; 1.1442x over previous
//
#include <hip/hip_runtime.h>
#include <hip/hip_bf16.h>

#define HDIM 4096
#define DHEAD 128
#define NQH 32
#define NKVH 8
#define SEQ 2048
#define QKVN 6144  // fused N = 4096 + 1024 + 1024

typedef __bf16 bf16x8 __attribute__((ext_vector_type(8)));
typedef unsigned short ushort8 __attribute__((ext_vector_type(8)));
typedef float f32x4 __attribute__((ext_vector_type(4)));
typedef float f32x16 __attribute__((ext_vector_type(16)));
typedef unsigned int u32x4 __attribute__((ext_vector_type(4)));

// wait until <= N vector-memory ops outstanding (lgkm/exp not waited)
#define WAIT_VM(N) __builtin_amdgcn_s_waitcnt(0xF70 | (N))

__device__ inline unsigned short f2bf(float f) {
    unsigned u = __float_as_uint(f);
    u += 0x7fffu + ((u >> 16) & 1u);
    return (unsigned short)(u >> 16);
}

// pack two f32 -> {lo:bf16, hi:bf16} in one u32 (low word = first arg)
__device__ inline unsigned cvtpk(float lo, float hi) {
    unsigned r;
    asm("v_cvt_pk_bf16_f32 %0, %1, %2" : "=v"(r) : "v"(lo), "v"(hi));
    return r;
}

__device__ inline void gload16(const void* g, void* l) {
    __builtin_amdgcn_global_load_lds(
        (const __attribute__((address_space(1))) unsigned int*)g,
        (__attribute__((address_space(3))) unsigned int*)l, 16, 0, 0);
}

// ---------------- transpose + fp32->bf16 convert: in[K][N] -> out[N][K] ----------------
__global__ void transpose_convert(const float* __restrict__ in, unsigned short* __restrict__ out,
                                  int K, int N) {
    __shared__ float tile[32][33];
    const int n0 = blockIdx.x * 32, k0 = blockIdx.y * 32;
    const int tx = threadIdx.x, ty = threadIdx.y;  // 32 x 8
    for (int r = 0; r < 32; r += 8)
        tile[ty + r][tx] = in[(size_t)(k0 + ty + r) * N + n0 + tx];
    __syncthreads();
    for (int r = 0; r < 32; r += 8)
        out[(size_t)(n0 + ty + r) * K + k0 + tx] = f2bf(tile[tx][ty + r]);
}

// ---------------- V transpose: fp32 qkv-fused row -> bf16 (NKVH, D, S) ----------------
__global__ void transpose_v(const float* __restrict__ qkvf, unsigned short* __restrict__ vbt) {
    __shared__ float tile[32][33];
    const int s0 = blockIdx.x * 32, d0 = blockIdx.y * 32, hv = blockIdx.z;
    const int tx = threadIdx.x, ty = threadIdx.y;  // 32 x 8
    for (int r = 0; r < 32; r += 8)
        tile[ty + r][tx] = qkvf[(size_t)(s0 + ty + r) * QKVN + 5120 + hv * DHEAD + d0 + tx];
    __syncthreads();
    for (int r = 0; r < 32; r += 8)
        vbt[((size_t)hv * DHEAD + d0 + ty + r) * SEQ + s0 + tx] = f2bf(tile[tx][ty + r]);
}

// ---------------- LayerNorm: fp32 (S,H) -> bf16 (S,H) ----------------
__global__ __launch_bounds__(256) void layernorm_kernel(
    const float* __restrict__ hs, const float* __restrict__ w, const float* __restrict__ b,
    unsigned short* __restrict__ xb) {
    const int s = blockIdx.x;
    const float* row = hs + (size_t)s * HDIM;
    const int t = threadIdx.x;
    float vals[16];
    float sum = 0.f, sq = 0.f;
    for (int j = 0; j < 16; j++) {
        float v = row[j * 256 + t];
        vals[j] = v; sum += v; sq += v * v;
    }
    for (int off = 1; off < 64; off <<= 1) {
        sum += __shfl_xor(sum, off);
        sq  += __shfl_xor(sq, off);
    }
    __shared__ float ps[4], pq[4];
    if ((t & 63) == 0) { ps[t >> 6] = sum; pq[t >> 6] = sq; }
    __syncthreads();
    sum = ps[0] + ps[1] + ps[2] + ps[3];
    sq  = pq[0] + pq[1] + pq[2] + pq[3];
    const float mu = sum * (1.0f / HDIM);
    const float var = sq * (1.0f / HDIM) - mu * mu;
    const float rs = rsqrtf(var + 1e-5f);
    for (int j = 0; j < 16; j++) {
        int i = j * 256 + t;
        xb[(size_t)s * HDIM + i] = f2bf((vals[j] - mu) * rs * w[i] + b[i]);
    }
}

// ---------------- 8-phase pipelined GEMM: C = A[M,K] * Bt[N,K]^T (bf16 in, fp32 out) ----
// BM=BN=256, BK=64, 512 thr = 8 waves (2M x 4N), wave tile 128x64. (r6 schedule, r7 2D-XCD)
__global__ __launch_bounds__(512, 2) void gemm8p(
    const unsigned short* __restrict__ A, const unsigned short* __restrict__ Bt,
    float* __restrict__ C, int N, int lda, int Keff, int nbx,
    int gridInner, int ksliceElems, long long cSliceStride) {
    __shared__ __align__(16) unsigned short Abuf[2 * 2 * 256 * 32];  // 64 KB
    __shared__ __align__(16) unsigned short Bbuf[2 * 2 * 256 * 32];  // 64 KB

    const int slice = blockIdx.x / gridInner;
    const int inner = blockIdx.x % gridInner;
    const int cbx = nbx >> 3;
    const int xcd = inner & 7, k = inner >> 3;
    const int bx = xcd * cbx + (k % cbx);
    const int by = k / cbx;
    const int row0 = by * 256, col0 = bx * 256;
    A  += (size_t)slice * ksliceElems;
    Bt += (size_t)slice * ksliceElems;
    C  += (size_t)slice * cSliceStride;

    const int t = threadIdx.x, lane = t & 63, w = t >> 6;
    const int wr = w >> 2, wc = w & 3;
    const int r16 = lane & 15, kq = lane >> 4;

    const int srow = t >> 2;
    const int scsw = (t & 3) ^ ((srow >> 1) & 3);
    const unsigned short* aStage = A  + (size_t)(row0 + srow) * lda + scsw * 8;
    const unsigned short* bStage = Bt + (size_t)(col0 + srow) * lda + scsw * 8;
    const size_t half = 128 * (size_t)lda;
    const int wdst = w * 512;

    const int NT = Keff / 64;

#define STAGE(p0, ldsbuf, bufidx, kh, kt) do {                                  \
        const unsigned short* _g = (p0) + (size_t)(kt) * 64 + (kh) * 32;        \
        gload16(_g,        &ldsbuf[((bufidx) * 2 + (kh)) * 8192 + wdst]);       \
        gload16(_g + half, &ldsbuf[((bufidx) * 2 + (kh)) * 8192 + 4096 + wdst]);\
    } while (0)

#define LDA4(dst, bufidx, kh, ih) {                                             \
        _Pragma("unroll") for (int i = 0; i < 4; i++) {                         \
            int arow = wr * 128 + (ih) * 64 + i * 16 + r16;                     \
            dst[i] = *(const bf16x8*)&Abuf[((bufidx) * 2 + (kh)) * 8192 +       \
                     arow * 32 + (kq ^ ((arow >> 1) & 3)) * 8];                 \
        } }

#define LDB4(dst, bufidx, kh) {                                                 \
        _Pragma("unroll") for (int j = 0; j < 4; j++) {                         \
            int brow = wc * 64 + j * 16 + r16;                                  \
            dst[j] = *(const bf16x8*)&Bbuf[((bufidx) * 2 + (kh)) * 8192 +       \
                     brow * 32 + (kq ^ ((brow >> 1) & 3)) * 8];                 \
        } }

#define MM16(ih, av, bv) {                                                      \
        __builtin_amdgcn_s_setprio(1);                                          \
        _Pragma("unroll") for (int i = 0; i < 4; i++)                           \
            _Pragma("unroll") for (int j = 0; j < 4; j++)                       \
                acc[(ih) * 4 + i][j] = __builtin_amdgcn_mfma_f32_16x16x32_bf16( \
                    av[i], bv[j], acc[(ih) * 4 + i][j], 0, 0, 0);               \
        __builtin_amdgcn_s_setprio(0); }

    STAGE(aStage, Abuf, 0, 0, 0);
    STAGE(bStage, Bbuf, 0, 0, 0);
    STAGE(aStage, Abuf, 0, 1, 0);
    STAGE(bStage, Bbuf, 0, 1, 0);
    WAIT_VM(4);
    __builtin_amdgcn_s_barrier();

    f32x4 acc[8][4] = {};
    for (int kt = 0; kt < NT; ++kt) {
        const int cur = kt & 1, nxt = cur ^ 1;
        const bool nl = (kt + 1 < NT);
        bf16x8 a0[4], a1[4], bv[4];
        LDA4(a0, cur, 0, 0);
        LDB4(bv, cur, 0);
        if (nl) STAGE(aStage, Abuf, nxt, 0, kt + 1);
        MM16(0, a0, bv);
        LDA4(a1, cur, 0, 1);
        if (nl) STAGE(bStage, Bbuf, nxt, 0, kt + 1);
        MM16(1, a1, bv);
        if (nl) WAIT_VM(4); else WAIT_VM(0);
        __builtin_amdgcn_s_barrier();
        LDA4(a0, cur, 1, 0);
        LDB4(bv, cur, 1);
        if (nl) STAGE(aStage, Abuf, nxt, 1, kt + 1);
        MM16(0, a0, bv);
        LDA4(a1, cur, 1, 1);
        if (nl) STAGE(bStage, Bbuf, nxt, 1, kt + 1);
        MM16(1, a1, bv);
        if (nl) {
            WAIT_VM(4);
            __builtin_amdgcn_s_barrier();
        }
    }

    #pragma unroll
    for (int i = 0; i < 8; i++)
        #pragma unroll
        for (int j = 0; j < 4; j++)
            #pragma unroll
            for (int r = 0; r < 4; r++) {
                int row = row0 + wr * 128 + i * 16 + kq * 4 + r;
                int col = col0 + wc * 64 + j * 16 + r16;
                C[(size_t)row * N + col] = acc[i][j][r];
            }
#undef STAGE
#undef LDA4
#undef LDB4
#undef MM16
}

// ---------------- split-K reduce: out = a + b ----------------
__global__ __launch_bounds__(256) void reduce_add(const float* __restrict__ a,
                                                  const float* __restrict__ b,
                                                  float* __restrict__ o, int n) {
    int i = (blockIdx.x * 256 + threadIdx.x) * 4;
    const int stride = gridDim.x * 256 * 4;
    for (; i < n; i += stride) {
        f32x4 x = *(const f32x4*)&a[i];
        f32x4 y = *(const f32x4*)&b[i];
        x += y;
        *(f32x4*)&o[i] = x;
    }
}

// ---------------- RoPE + convert to head-major bf16 (reads fused qkv fp32) ----------------
__global__ void rope_convert(const float* __restrict__ qkvf,
                             unsigned short* __restrict__ qb, unsigned short* __restrict__ kb) {
    const int s = blockIdx.x;
    const int head = blockIdx.y;
    const int d = threadIdx.x;  // 0..63
    const float SCALE = 0.08838834764831845f;  // 1/sqrt(128)
    const float NLOG = -0.14391156831212787f;  // -ln(10000)/64
    float f = (float)s * __expf((float)d * NLOG);
    float sn, c;
    __sincosf(f, &sn, &c);
    if (head < NQH) {
        const float* src = qkvf + (size_t)s * QKVN + head * DHEAD;
        float x1 = src[d], x2 = src[d + 64];
        unsigned short* dst = qb + ((size_t)head * SEQ + s) * DHEAD;
        dst[d]      = f2bf((x1 * c - x2 * sn) * SCALE);
        dst[d + 64] = f2bf((x2 * c + x1 * sn) * SCALE);
    } else {
        const int hk = head - NQH;
        const float* src = qkvf + (size_t)s * QKVN + 4096 + hk * DHEAD;
        float x1 = src[d], x2 = src[d + 64];
        unsigned short* dst = kb + ((size_t)hk * SEQ + s) * DHEAD;
        dst[d]      = f2bf(x1 * c - x2 * sn);
        dst[d + 64] = f2bf(x2 * c + x1 * sn);
    }
}

// ---------------- Flash attention: swapped QK^T + in-register softmax (32x32 MFMA) -----
// Block = (head h, 128-row slab p): 4 warps x 32 q-rows. KVBLK=64.
// QK^T computed as mfma(K, Q) -> S^T: lane owns q = lane&31; 32 scores/lane
// (2 k-tiles x f32x16, k = (reg&3)+8*(reg>>2)+4*(lane>>5)). Softmax fully in-register:
// row-reduce = local 31 ops + shfl_xor(32); per-q redistribution via __shfl of scalars.
// P repacked to PV A-frags with cvt_pk_bf16 (16) + shfl_xor(32) (16) + static selects.
// No P LDS roundtrip (r10 bottleneck: MfmaUtil 11%, latency-bound serial chain).
__global__ __launch_bounds__(256, 2) void attention_kernel(
    const unsigned short* __restrict__ Q, const unsigned short* __restrict__ K,
    const unsigned short* __restrict__ Vt, unsigned short* __restrict__ O) {
    __shared__ __align__(16) unsigned short Ks[64 * 128];  // [kcol][d], swizzled
    __shared__ __align__(16) unsigned short Vs[128 * 64];  // [d][k],   swizzled
    const int h = blockIdx.x & 31;
    const int p = 15 - (blockIdx.x >> 5);   // LPT: largest slabs first
    const int t = threadIdx.x, lane = t & 63, w = t >> 6;
    const int q31 = lane & 31, h2 = lane >> 5;
    const int q0w = p * 128 + w * 32;
    const int kbw = 2 * p + (w >> 1);       // this warp's diagonal kb
    const int kbmax = 2 * p + 1;            // block's last kb
    const int hkv = h >> 2;

    // Q frags (B operand of swapped QK): lane holds Q[q0w+q31][ds*16 + h2*8 .. +7]
    bf16x8 qf[8];
    {
        const unsigned short* qrow = Q + ((size_t)h * SEQ + q0w + q31) * DHEAD + h2 * 8;
        #pragma unroll
        for (int ds = 0; ds < 8; ds++) qf[ds] = *(const bf16x8*)&qrow[ds * 16];
    }

    f32x16 oacc[4] = {};   // O^: D[m=q(reg-pattern)][n=d=nt*32+q31]
    float m_r = -1e30f, l_r = 0.f;   // state for q = q0w + q31 (lane-local)

    const unsigned short* Kg = K + (size_t)hkv * SEQ * DHEAD;
    const unsigned short* Vg = Vt + (size_t)hkv * DHEAD * SEQ;

    // staging tasks (256 thr, 4 each): K 64rows x 16ch, V 128rows x 8ch
    const int krow = t >> 4, kch = t & 15;
    const int vrow = t >> 3, vch = t & 7;
    ushort8 kreg[4], vreg[4];
    #pragma unroll
    for (int pp = 0; pp < 4; pp++) {
        kreg[pp] = *(const ushort8*)&Kg[(size_t)(pp * 16 + krow) * DHEAD + kch * 8];
        vreg[pp] = *(const ushort8*)&Vg[(size_t)(pp * 32 + vrow) * SEQ + vch * 8];
    }

    for (int kb = 0; kb <= kbmax; ++kb) {
        __syncthreads();
        #pragma unroll
        for (int pp = 0; pp < 4; pp++) {
            int row = pp * 16 + krow;
            *(ushort8*)&Ks[row * 128 + ((kch ^ (row & 7)) * 8)] = kreg[pp];
            int vr = pp * 32 + vrow;
            *(ushort8*)&Vs[vr * 64 + ((vch ^ (vr & 7)) * 8)] = vreg[pp];
        }
        if (kb < kbmax) {
            #pragma unroll
            for (int pp = 0; pp < 4; pp++) {
                kreg[pp] = *(const ushort8*)&Kg[(size_t)((kb + 1) * 64 + pp * 16 + krow) * DHEAD + kch * 8];
                vreg[pp] = *(const ushort8*)&Vg[(size_t)(pp * 32 + vrow) * SEQ + (kb + 1) * 64 + vch * 8];
            }
        }
        __syncthreads();
        if (kb > kbw) continue;  // fully-masked for this warp; barriers stay matched

        // ---- QK^T (swapped): S^T tiles s0 (k 0..31), s1 (k 32..63) ----
        f32x16 s0 = {}, s1 = {};
        #pragma unroll
        for (int ds = 0; ds < 8; ds++) {
            int r0 = q31;                 // k-row tile 0
            int c0 = (ds * 2 + h2) ^ (r0 & 7);
            bf16x8 kf0 = *(const bf16x8*)&Ks[r0 * 128 + c0 * 8];
            s0 = __builtin_amdgcn_mfma_f32_32x32x16_bf16(kf0, qf[ds], s0, 0, 0, 0);
            int r1 = 32 + q31;            // k-row tile 1
            int c1 = (ds * 2 + h2) ^ (r1 & 7);
            bf16x8 kf1 = *(const bf16x8*)&Ks[r1 * 128 + c1 * 8];
            s1 = __builtin_amdgcn_mfma_f32_32x32x16_bf16(kf1, qf[ds], s1, 0, 0, 0);
        }
        // ---- causal mask (diagonal tile only) ----
        if (kb == kbw) {
            const int qg = q0w + q31;
            #pragma unroll
            for (int r = 0; r < 16; r++) {
                int kpos = (r & 3) + 8 * (r >> 2) + 4 * h2;
                s0[r] = (kb * 64 + kpos > qg) ? -1e30f : s0[r];
                s1[r] = (kb * 64 + 32 + kpos > qg) ? -1e30f : s1[r];
            }
        }
        // ---- in-register online softmax (row q = q31, split across lane halves) ----
        float pm = -1e30f;
        #pragma unroll
        for (int r = 0; r < 16; r++) pm = fmaxf(pm, fmaxf(s0[r], s1[r]));
        pm = fmaxf(pm, __shfl_xor(pm, 32));
        bool grow = pm > m_r + 8.f;   // T13 defer-max
        if (__any(grow)) {
            float mn = fmaxf(m_r, pm);
            float sc = __expf(m_r - mn);
            l_r *= sc;
            float scr[16];
            #pragma unroll
            for (int r = 0; r < 16; r++) scr[r] = __shfl(sc, (r & 3) + 8 * (r >> 2) + 4 * h2);
            #pragma unroll
            for (int nt = 0; nt < 4; nt++)
                #pragma unroll
                for (int r = 0; r < 16; r++) oacc[nt][r] *= scr[r];
            m_r = mn;
        }
        float sum = 0.f;
        #pragma unroll
        for (int r = 0; r < 16; r++) {
            s0[r] = __expf(s0[r] - m_r); sum += s0[r];
            s1[r] = __expf(s1[r] - m_r); sum += s1[r];
        }
        sum += __shfl_xor(sum, 32);
        l_r += sum;
        // ---- pack P to bf16 words; exchange halves; assemble PV A-frags ----
        unsigned ow0[8], ow1[8];
        #pragma unroll
        for (int a = 0; a < 4; a++) {
            ow0[a * 2 + 0] = cvtpk(s0[4 * a + 0], s0[4 * a + 1]);
            ow0[a * 2 + 1] = cvtpk(s0[4 * a + 2], s0[4 * a + 3]);
            ow1[a * 2 + 0] = cvtpk(s1[4 * a + 0], s1[4 * a + 1]);
            ow1[a * 2 + 1] = cvtpk(s1[4 * a + 2], s1[4 * a + 3]);
        }
        unsigned pw0[8], pw1[8];
        #pragma unroll
        for (int i = 0; i < 8; i++) {
            pw0[i] = __shfl_xor((int)ow0[i], 32);
            pw1[i] = __shfl_xor((int)ow1[i], 32);
        }
        bf16x8 pf[4];
        const bool lo = (h2 == 0);
        #pragma unroll
        for (int sub = 0; sub < 2; sub++) {
            int b0 = 2 * sub, b1 = 2 * sub + 1;
            u32x4 t0, t1;
            t0.x = lo ? ow0[b0 * 2 + 0] : pw0[b1 * 2 + 0];
            t0.y = lo ? ow0[b0 * 2 + 1] : pw0[b1 * 2 + 1];
            t0.z = lo ? pw0[b0 * 2 + 0] : ow0[b1 * 2 + 0];
            t0.w = lo ? pw0[b0 * 2 + 1] : ow0[b1 * 2 + 1];
            pf[sub] = __builtin_bit_cast(bf16x8, t0);
            t1.x = lo ? ow1[b0 * 2 + 0] : pw1[b1 * 2 + 0];
            t1.y = lo ? ow1[b0 * 2 + 1] : pw1[b1 * 2 + 1];
            t1.z = lo ? pw1[b0 * 2 + 0] : ow1[b1 * 2 + 0];
            t1.w = lo ? pw1[b0 * 2 + 1] : ow1[b1 * 2 + 1];
            pf[2 + sub] = __builtin_bit_cast(bf16x8, t1);
        }
        // ---- PV: O[q][d] += P[q][k] V[k][d]; B-frag from Vs ----
        #pragma unroll
        for (int nt = 0; nt < 4; nt++) {
            int vr2 = nt * 32 + q31;
            #pragma unroll
            for (int kt16 = 0; kt16 < 4; kt16++) {
                int vc2 = (kt16 * 2 + h2) ^ (vr2 & 7);
                bf16x8 vf = *(const bf16x8*)&Vs[vr2 * 64 + vc2 * 8];
                oacc[nt] = __builtin_amdgcn_mfma_f32_32x32x16_bf16(pf[kt16], vf, oacc[nt], 0, 0, 0);
            }
        }
    }
    // ---- epilogue: normalize (per-q l via shfl) and write ----
    float inv = 1.0f / l_r;
    float invr[16];
    #pragma unroll
    for (int r = 0; r < 16; r++) invr[r] = __shfl(inv, (r & 3) + 8 * (r >> 2) + 4 * h2);
    #pragma unroll
    for (int nt = 0; nt < 4; nt++)
        #pragma unroll
        for (int r = 0; r < 16; r++) {
            int qg = q0w + (r & 3) + 8 * (r >> 2) + 4 * h2;
            O[(size_t)qg * HDIM + h * DHEAD + nt * 32 + q31] = f2bf(oacc[nt][r] * invr[r]);
        }
}

extern "C" void kernel_launch(void* const* d_in, const int* in_sizes, int n_in,
                              void* d_out, int out_size, void* d_ws, size_t ws_size,
                              hipStream_t stream) {
    const float* hs  = (const float*)d_in[0];
    const float* lnw = (const float*)d_in[1];
    const float* lnb = (const float*)d_in[2];
    const float* wq  = (const float*)d_in[3];
    const float* wk  = (const float*)d_in[4];
    const float* wv  = (const float*)d_in[5];
    const float* wo  = (const float*)d_in[6];
    float* out = (float*)d_out;

    char* ws = (char*)d_ws;
    size_t off = 0;
    auto alloc = [&](size_t bytes) {
        void* p = ws + off;
        off += (bytes + 255) & ~(size_t)255;
        return p;
    };
    unsigned short* xb   = (unsigned short*)alloc((size_t)SEQ * HDIM * 2);
    // wqT/wkT/wvT contiguous -> fused [6144][4096] B matrix
    unsigned short* wqT  = (unsigned short*)alloc((size_t)HDIM * (NQH * DHEAD) * 2);
    unsigned short* wkT  = (unsigned short*)alloc((size_t)HDIM * (NKVH * DHEAD) * 2);
    unsigned short* wvT  = (unsigned short*)alloc((size_t)HDIM * (NKVH * DHEAD) * 2);
    unsigned short* woT  = (unsigned short*)alloc((size_t)(NQH * DHEAD) * HDIM * 2);
    float* qkvf          = (float*)alloc((size_t)SEQ * QKVN * 4);
    unsigned short* qbuf = (unsigned short*)alloc((size_t)NQH * SEQ * DHEAD * 2);
    unsigned short* kbuf = (unsigned short*)alloc((size_t)NKVH * SEQ * DHEAD * 2);
    unsigned short* vbt  = (unsigned short*)alloc((size_t)NKVH * DHEAD * SEQ * 2);
    unsigned short* attnb = (unsigned short*)qkvf;  // reuse fused-fp32 region after rope/v-transpose
    // split-K partials for O-proj: exactly 64 MiB, overlays xb+wqT+wkT+wvT (dead by then)
    float* cpart = (float*)xb;

    dim3 tb(32, 8);
    transpose_convert<<<dim3(4096 / 32, 4096 / 32), tb, 0, stream>>>(wq, wqT, 4096, 4096);
    transpose_convert<<<dim3(1024 / 32, 4096 / 32), tb, 0, stream>>>(wk, wkT, 4096, 1024);
    transpose_convert<<<dim3(1024 / 32, 4096 / 32), tb, 0, stream>>>(wv, wvT, 4096, 1024);
    transpose_convert<<<dim3(4096 / 32, 4096 / 32), tb, 0, stream>>>(wo, woT, 4096, 4096);

    layernorm_kernel<<<SEQ, 256, 0, stream>>>(hs, lnw, lnb, xb);

    // fused QKV projection: [2048][4096] x [6144][4096]^T -> [2048][6144]
    gemm8p<<<(2048 / 256) * (QKVN / 256), 512, 0, stream>>>(
        xb, wqT, qkvf, QKVN, 4096, 4096, QKVN / 256, (2048 / 256) * (QKVN / 256), 0, 0);

    rope_convert<<<dim3(SEQ, NQH + NKVH), 64, 0, stream>>>(qkvf, qbuf, kbuf);
    transpose_v<<<dim3(SEQ / 32, DHEAD / 32, NKVH), tb, 0, stream>>>(qkvf, vbt);

    // swapped-QK attention: grid = 32 heads x 16 q-slabs (128 rows each), 4 warps/block
    attention_kernel<<<NQH * 16, 256, 0, stream>>>(qbuf, kbuf, vbt, attnb);

    // O-proj with split-K=2: grid 256 = 2 slices x 128 blocks, K=2048 each
    gemm8p<<<2 * (2048 / 256) * (4096 / 256), 512, 0, stream>>>(
        attnb, woT, cpart, 4096, 4096, 2048, 4096 / 256,
        (2048 / 256) * (4096 / 256), 2048, (long long)2048 * 4096);
    reduce_add<<<2048, 256, 0, stream>>>(cpart, cpart + (size_t)2048 * 4096, out,
                                         2048 * 4096);
}

// Round 12
// 325.518 us; speedup vs baseline: 1.2712x; 1.0451x over previous
//
#include <hip/hip_runtime.h>
#include <hip/hip_bf16.h>

#define HDIM 4096
#define DHEAD 128
#define NQH 32
#define NKVH 8
#define SEQ 2048
#define QKVN 6144  // fused N = 4096 + 1024 + 1024

typedef __bf16 bf16x8 __attribute__((ext_vector_type(8)));
typedef unsigned short ushort8 __attribute__((ext_vector_type(8)));
typedef float f32x4 __attribute__((ext_vector_type(4)));
typedef float f32x16 __attribute__((ext_vector_type(16)));
typedef unsigned int u32x4 __attribute__((ext_vector_type(4)));

// wait until <= N vector-memory ops outstanding (lgkm/exp not waited)
#define WAIT_VM(N) __builtin_amdgcn_s_waitcnt(0xF70 | (N))

__device__ inline unsigned short f2bf(float f) {
    unsigned u = __float_as_uint(f);
    u += 0x7fffu + ((u >> 16) & 1u);
    return (unsigned short)(u >> 16);
}

// pack two f32 -> {lo:bf16, hi:bf16} in one u32 (low word = first arg)
__device__ inline unsigned cvtpk(float lo, float hi) {
    unsigned r;
    asm("v_cvt_pk_bf16_f32 %0, %1, %2" : "=v"(r) : "v"(lo), "v"(hi));
    return r;
}

__device__ inline void gload16(const void* g, void* l) {
    __builtin_amdgcn_global_load_lds(
        (const __attribute__((address_space(1))) unsigned int*)g,
        (__attribute__((address_space(3))) unsigned int*)l, 16, 0, 0);
}

// ---------------- transpose + fp32->bf16 convert: in[K][N] -> out[N][K] ----------------
__global__ void transpose_convert(const float* __restrict__ in, unsigned short* __restrict__ out,
                                  int K, int N) {
    __shared__ float tile[32][33];
    const int n0 = blockIdx.x * 32, k0 = blockIdx.y * 32;
    const int tx = threadIdx.x, ty = threadIdx.y;  // 32 x 8
    for (int r = 0; r < 32; r += 8)
        tile[ty + r][tx] = in[(size_t)(k0 + ty + r) * N + n0 + tx];
    __syncthreads();
    for (int r = 0; r < 32; r += 8)
        out[(size_t)(n0 + ty + r) * K + k0 + tx] = f2bf(tile[tx][ty + r]);
}

// ---------------- V transpose: fp32 qkv-fused row -> bf16 (NKVH, D, S) ----------------
__global__ void transpose_v(const float* __restrict__ qkvf, unsigned short* __restrict__ vbt) {
    __shared__ float tile[32][33];
    const int s0 = blockIdx.x * 32, d0 = blockIdx.y * 32, hv = blockIdx.z;
    const int tx = threadIdx.x, ty = threadIdx.y;  // 32 x 8
    for (int r = 0; r < 32; r += 8)
        tile[ty + r][tx] = qkvf[(size_t)(s0 + ty + r) * QKVN + 5120 + hv * DHEAD + d0 + tx];
    __syncthreads();
    for (int r = 0; r < 32; r += 8)
        vbt[((size_t)hv * DHEAD + d0 + ty + r) * SEQ + s0 + tx] = f2bf(tile[tx][ty + r]);
}

// ---------------- LayerNorm: fp32 (S,H) -> bf16 (S,H) ----------------
__global__ __launch_bounds__(256) void layernorm_kernel(
    const float* __restrict__ hs, const float* __restrict__ w, const float* __restrict__ b,
    unsigned short* __restrict__ xb) {
    const int s = blockIdx.x;
    const float* row = hs + (size_t)s * HDIM;
    const int t = threadIdx.x;
    float vals[16];
    float sum = 0.f, sq = 0.f;
    for (int j = 0; j < 16; j++) {
        float v = row[j * 256 + t];
        vals[j] = v; sum += v; sq += v * v;
    }
    for (int off = 1; off < 64; off <<= 1) {
        sum += __shfl_xor(sum, off);
        sq  += __shfl_xor(sq, off);
    }
    __shared__ float ps[4], pq[4];
    if ((t & 63) == 0) { ps[t >> 6] = sum; pq[t >> 6] = sq; }
    __syncthreads();
    sum = ps[0] + ps[1] + ps[2] + ps[3];
    sq  = pq[0] + pq[1] + pq[2] + pq[3];
    const float mu = sum * (1.0f / HDIM);
    const float var = sq * (1.0f / HDIM) - mu * mu;
    const float rs = rsqrtf(var + 1e-5f);
    for (int j = 0; j < 16; j++) {
        int i = j * 256 + t;
        xb[(size_t)s * HDIM + i] = f2bf((vals[j] - mu) * rs * w[i] + b[i]);
    }
}

// ---------------- 8-phase pipelined GEMM (QKV): BM=BN=256, BK=64 (r6 schedule) ----------
__global__ __launch_bounds__(512, 2) void gemm8p(
    const unsigned short* __restrict__ A, const unsigned short* __restrict__ Bt,
    float* __restrict__ C, int N, int lda, int Keff, int nbx,
    int gridInner, int ksliceElems, long long cSliceStride) {
    __shared__ __align__(16) unsigned short Abuf[2 * 2 * 256 * 32];  // 64 KB
    __shared__ __align__(16) unsigned short Bbuf[2 * 2 * 256 * 32];  // 64 KB

    const int slice = blockIdx.x / gridInner;
    const int inner = blockIdx.x % gridInner;
    const int cbx = nbx >> 3;
    const int xcd = inner & 7, k = inner >> 3;
    const int bx = xcd * cbx + (k % cbx);
    const int by = k / cbx;
    const int row0 = by * 256, col0 = bx * 256;
    A  += (size_t)slice * ksliceElems;
    Bt += (size_t)slice * ksliceElems;
    C  += (size_t)slice * cSliceStride;

    const int t = threadIdx.x, lane = t & 63, w = t >> 6;
    const int wr = w >> 2, wc = w & 3;
    const int r16 = lane & 15, kq = lane >> 4;

    const int srow = t >> 2;
    const int scsw = (t & 3) ^ ((srow >> 1) & 3);
    const unsigned short* aStage = A  + (size_t)(row0 + srow) * lda + scsw * 8;
    const unsigned short* bStage = Bt + (size_t)(col0 + srow) * lda + scsw * 8;
    const size_t half = 128 * (size_t)lda;
    const int wdst = w * 512;

    const int NT = Keff / 64;

#define STAGE(p0, ldsbuf, bufidx, kh, kt) do {                                  \
        const unsigned short* _g = (p0) + (size_t)(kt) * 64 + (kh) * 32;        \
        gload16(_g,        &ldsbuf[((bufidx) * 2 + (kh)) * 8192 + wdst]);       \
        gload16(_g + half, &ldsbuf[((bufidx) * 2 + (kh)) * 8192 + 4096 + wdst]);\
    } while (0)

#define LDA4(dst, bufidx, kh, ih) {                                             \
        _Pragma("unroll") for (int i = 0; i < 4; i++) {                         \
            int arow = wr * 128 + (ih) * 64 + i * 16 + r16;                     \
            dst[i] = *(const bf16x8*)&Abuf[((bufidx) * 2 + (kh)) * 8192 +       \
                     arow * 32 + (kq ^ ((arow >> 1) & 3)) * 8];                 \
        } }

#define LDB4(dst, bufidx, kh) {                                                 \
        _Pragma("unroll") for (int j = 0; j < 4; j++) {                         \
            int brow = wc * 64 + j * 16 + r16;                                  \
            dst[j] = *(const bf16x8*)&Bbuf[((bufidx) * 2 + (kh)) * 8192 +       \
                     brow * 32 + (kq ^ ((brow >> 1) & 3)) * 8];                 \
        } }

#define MM16(ih, av, bv) {                                                      \
        __builtin_amdgcn_s_setprio(1);                                          \
        _Pragma("unroll") for (int i = 0; i < 4; i++)                           \
            _Pragma("unroll") for (int j = 0; j < 4; j++)                       \
                acc[(ih) * 4 + i][j] = __builtin_amdgcn_mfma_f32_16x16x32_bf16( \
                    av[i], bv[j], acc[(ih) * 4 + i][j], 0, 0, 0);               \
        __builtin_amdgcn_s_setprio(0); }

    STAGE(aStage, Abuf, 0, 0, 0);
    STAGE(bStage, Bbuf, 0, 0, 0);
    STAGE(aStage, Abuf, 0, 1, 0);
    STAGE(bStage, Bbuf, 0, 1, 0);
    WAIT_VM(4);
    __builtin_amdgcn_s_barrier();

    f32x4 acc[8][4] = {};
    for (int kt = 0; kt < NT; ++kt) {
        const int cur = kt & 1, nxt = cur ^ 1;
        const bool nl = (kt + 1 < NT);
        bf16x8 a0[4], a1[4], bv[4];
        LDA4(a0, cur, 0, 0);
        LDB4(bv, cur, 0);
        if (nl) STAGE(aStage, Abuf, nxt, 0, kt + 1);
        MM16(0, a0, bv);
        LDA4(a1, cur, 0, 1);
        if (nl) STAGE(bStage, Bbuf, nxt, 0, kt + 1);
        MM16(1, a1, bv);
        if (nl) WAIT_VM(4); else WAIT_VM(0);
        __builtin_amdgcn_s_barrier();
        LDA4(a0, cur, 1, 0);
        LDB4(bv, cur, 1);
        if (nl) STAGE(aStage, Abuf, nxt, 1, kt + 1);
        MM16(0, a0, bv);
        LDA4(a1, cur, 1, 1);
        if (nl) STAGE(bStage, Bbuf, nxt, 1, kt + 1);
        MM16(1, a1, bv);
        if (nl) {
            WAIT_VM(4);
            __builtin_amdgcn_s_barrier();
        }
    }

    #pragma unroll
    for (int i = 0; i < 8; i++)
        #pragma unroll
        for (int j = 0; j < 4; j++)
            #pragma unroll
            for (int r = 0; r < 4; r++) {
                int row = row0 + wr * 128 + i * 16 + kq * 4 + r;
                int col = col0 + wc * 64 + j * 16 + r16;
                C[(size_t)row * N + col] = acc[i][j][r];
            }
#undef STAGE
#undef LDA4
#undef LDB4
#undef MM16
}

// ---------------- Deep-pipelined GEMM (O-proj): BM=256, BN=128, BK=64 ------------------
// 512 thr = 8 waves (4M x 2N), wave tile 64x64. 3 LDS buffers (A 96KB + B 48KB = 144KB),
// full-K-tile staging 2 tiles ahead (6 loads/thread/tile), ONE gate per K-tile:
// WAIT_VM(6) forces tile t+1 landed while t+2's 6 loads stay in flight (slack ~2 tiles
// of compute ~ HBM latency). Full 8-way XOR swizzle (8 chunks at BK=64), pre-swizzled
// global source, linear LDS dest (wave-uniform base + lane*16B).
__global__ __launch_bounds__(512, 2) void gemm8n(
    const unsigned short* __restrict__ A, const unsigned short* __restrict__ Bt,
    float* __restrict__ C, int N, int lda, int Keff, int nbx) {
    __shared__ __align__(16) unsigned short Abuf[3][256 * 64];  // 96 KB
    __shared__ __align__(16) unsigned short Bbuf[3][128 * 64];  // 48 KB

    const int inner = blockIdx.x;
    const int cbx = nbx >> 3;
    const int xcd = inner & 7, kk = inner >> 3;
    const int bx = xcd * cbx + (kk % cbx);
    const int by = kk / cbx;
    const int row0 = by * 256, col0 = bx * 128;

    const int t = threadIdx.x, lane = t & 63, w = t >> 6;
    const int wr = w >> 1, wc = w & 1;          // 4M x 2N wave grid
    const int r16 = lane & 15, kq = lane >> 4;

    // staging: thread t covers row srow (+64*i), chunk (t&7) pre-swizzled (full 8-way)
    const int srow = t >> 3;                    // 0..63
    const int scsw = (t & 7) ^ (srow & 7);      // (i*64+srow)&7 == srow&7
    const unsigned short* aStage = A  + (size_t)(row0 + srow) * lda + scsw * 8;
    const unsigned short* bStage = Bt + (size_t)(col0 + srow) * lda + scsw * 8;
    const size_t rstep = 64 * (size_t)lda;

    const int NT = Keff / 64;

#define NSTG_H0(bufi, kt) {                                                     \
        gload16(aStage + (size_t)(kt) * 64,             &Abuf[bufi][0 * 4096 + w * 512]); \
        gload16(aStage + (size_t)(kt) * 64 + rstep,     &Abuf[bufi][1 * 4096 + w * 512]); \
        gload16(bStage + (size_t)(kt) * 64,             &Bbuf[bufi][0 * 4096 + w * 512]); }
#define NSTG_H1(bufi, kt) {                                                     \
        gload16(aStage + (size_t)(kt) * 64 + 2 * rstep, &Abuf[bufi][2 * 4096 + w * 512]); \
        gload16(aStage + (size_t)(kt) * 64 + 3 * rstep, &Abuf[bufi][3 * 4096 + w * 512]); \
        gload16(bStage + (size_t)(kt) * 64 + rstep,     &Bbuf[bufi][1 * 4096 + w * 512]); }

#define NLDA(dst, bufi, kh) { _Pragma("unroll") for (int i = 0; i < 4; i++) {   \
        int ar = wr * 64 + i * 16 + r16;                                        \
        dst[i] = *(const bf16x8*)&Abuf[bufi][ar * 64 + (((kh) * 4 + kq) ^ (ar & 7)) * 8]; } }
#define NLDB(dst, bufi, kh) { _Pragma("unroll") for (int j = 0; j < 4; j++) {   \
        int br = wc * 64 + j * 16 + r16;                                        \
        dst[j] = *(const bf16x8*)&Bbuf[bufi][br * 64 + (((kh) * 4 + kq) ^ (br & 7)) * 8]; } }

#define MMN(av, bv) {                                                           \
        __builtin_amdgcn_s_setprio(1);                                          \
        _Pragma("unroll") for (int i = 0; i < 4; i++)                           \
            _Pragma("unroll") for (int j = 0; j < 4; j++)                       \
                acc[i][j] = __builtin_amdgcn_mfma_f32_16x16x32_bf16(            \
                    av[i], bv[j], acc[i][j], 0, 0, 0);                          \
        __builtin_amdgcn_s_setprio(0); }

    // prologue: stage K-tiles 0 and 1 fully (6 loads each)
    NSTG_H0(0, 0); NSTG_H1(0, 0);
    NSTG_H0(1, 1); NSTG_H1(1, 1);
    WAIT_VM(6);  // T0 landed; T1's 6 in flight
    __builtin_amdgcn_s_barrier();

    f32x4 acc[4][4] = {};
    for (int kt = 0; kt < NT; ++kt) {
        const int cur = kt % 3, nx2 = (kt + 2) % 3;
        const bool pf = (kt + 2) < NT;
        bf16x8 av[4], bv[4];
        // ph0 (kh0): ds_read | stage half of T+2 | MFMA
        NLDA(av, cur, 0);
        NLDB(bv, cur, 0);
        if (pf) NSTG_H0(nx2, kt + 2);
        MMN(av, bv);
        // ph1 (kh1): ds_read | stage rest of T+2 | MFMA
        NLDA(av, cur, 1);
        NLDB(bv, cur, 1);
        if (pf) NSTG_H1(nx2, kt + 2);
        MMN(av, bv);
        // single gate per K-tile: T+1 landed, T+2 in flight
        if (kt + 1 < NT) {
            if (pf) WAIT_VM(6); else WAIT_VM(0);
            __builtin_amdgcn_s_barrier();
        }
    }

    #pragma unroll
    for (int i = 0; i < 4; i++)
        #pragma unroll
        for (int j = 0; j < 4; j++)
            #pragma unroll
            for (int r = 0; r < 4; r++) {
                int row = row0 + wr * 64 + i * 16 + kq * 4 + r;
                int col = col0 + wc * 64 + j * 16 + r16;
                C[(size_t)row * N + col] = acc[i][j][r];
            }
#undef NSTG_H0
#undef NSTG_H1
#undef NLDA
#undef NLDB
#undef MMN
}

// ---------------- RoPE + convert to head-major bf16 (reads fused qkv fp32) ----------------
__global__ void rope_convert(const float* __restrict__ qkvf,
                             unsigned short* __restrict__ qb, unsigned short* __restrict__ kb) {
    const int s = blockIdx.x;
    const int head = blockIdx.y;
    const int d = threadIdx.x;  // 0..63
    const float SCALE = 0.08838834764831845f;  // 1/sqrt(128)
    const float NLOG = -0.14391156831212787f;  // -ln(10000)/64
    float f = (float)s * __expf((float)d * NLOG);
    float sn, c;
    __sincosf(f, &sn, &c);
    if (head < NQH) {
        const float* src = qkvf + (size_t)s * QKVN + head * DHEAD;
        float x1 = src[d], x2 = src[d + 64];
        unsigned short* dst = qb + ((size_t)head * SEQ + s) * DHEAD;
        dst[d]      = f2bf((x1 * c - x2 * sn) * SCALE);
        dst[d + 64] = f2bf((x2 * c + x1 * sn) * SCALE);
    } else {
        const int hk = head - NQH;
        const float* src = qkvf + (size_t)s * QKVN + 4096 + hk * DHEAD;
        float x1 = src[d], x2 = src[d + 64];
        unsigned short* dst = kb + ((size_t)hk * SEQ + s) * DHEAD;
        dst[d]      = f2bf(x1 * c - x2 * sn);
        dst[d + 64] = f2bf(x2 * c + x1 * sn);
    }
}

// ---------------- Flash attention: swapped QK^T + in-register softmax (32x32 MFMA) -----
__global__ __launch_bounds__(256, 2) void attention_kernel(
    const unsigned short* __restrict__ Q, const unsigned short* __restrict__ K,
    const unsigned short* __restrict__ Vt, unsigned short* __restrict__ O) {
    __shared__ __align__(16) unsigned short Ks[64 * 128];  // [kcol][d], swizzled
    __shared__ __align__(16) unsigned short Vs[128 * 64];  // [d][k],   swizzled
    const int h = blockIdx.x & 31;
    const int p = 15 - (blockIdx.x >> 5);   // LPT: largest slabs first
    const int t = threadIdx.x, lane = t & 63, w = t >> 6;
    const int q31 = lane & 31, h2 = lane >> 5;
    const int q0w = p * 128 + w * 32;
    const int kbw = 2 * p + (w >> 1);       // this warp's diagonal kb
    const int kbmax = 2 * p + 1;            // block's last kb
    const int hkv = h >> 2;

    bf16x8 qf[8];
    {
        const unsigned short* qrow = Q + ((size_t)h * SEQ + q0w + q31) * DHEAD + h2 * 8;
        #pragma unroll
        for (int ds = 0; ds < 8; ds++) qf[ds] = *(const bf16x8*)&qrow[ds * 16];
    }

    f32x16 oacc[4] = {};
    float m_r = -1e30f, l_r = 0.f;

    const unsigned short* Kg = K + (size_t)hkv * SEQ * DHEAD;
    const unsigned short* Vg = Vt + (size_t)hkv * DHEAD * SEQ;

    const int krow = t >> 4, kch = t & 15;
    const int vrow = t >> 3, vch = t & 7;
    ushort8 kreg[4], vreg[4];
    #pragma unroll
    for (int pp = 0; pp < 4; pp++) {
        kreg[pp] = *(const ushort8*)&Kg[(size_t)(pp * 16 + krow) * DHEAD + kch * 8];
        vreg[pp] = *(const ushort8*)&Vg[(size_t)(pp * 32 + vrow) * SEQ + vch * 8];
    }

    for (int kb = 0; kb <= kbmax; ++kb) {
        __syncthreads();
        #pragma unroll
        for (int pp = 0; pp < 4; pp++) {
            int row = pp * 16 + krow;
            *(ushort8*)&Ks[row * 128 + ((kch ^ (row & 7)) * 8)] = kreg[pp];
            int vr = pp * 32 + vrow;
            *(ushort8*)&Vs[vr * 64 + ((vch ^ (vr & 7)) * 8)] = vreg[pp];
        }
        if (kb < kbmax) {
            #pragma unroll
            for (int pp = 0; pp < 4; pp++) {
                kreg[pp] = *(const ushort8*)&Kg[(size_t)((kb + 1) * 64 + pp * 16 + krow) * DHEAD + kch * 8];
                vreg[pp] = *(const ushort8*)&Vg[(size_t)(pp * 32 + vrow) * SEQ + (kb + 1) * 64 + vch * 8];
            }
        }
        __syncthreads();
        if (kb > kbw) continue;

        f32x16 s0 = {}, s1 = {};
        #pragma unroll
        for (int ds = 0; ds < 8; ds++) {
            int r0 = q31;
            int c0 = (ds * 2 + h2) ^ (r0 & 7);
            bf16x8 kf0 = *(const bf16x8*)&Ks[r0 * 128 + c0 * 8];
            s0 = __builtin_amdgcn_mfma_f32_32x32x16_bf16(kf0, qf[ds], s0, 0, 0, 0);
            int r1 = 32 + q31;
            int c1 = (ds * 2 + h2) ^ (r1 & 7);
            bf16x8 kf1 = *(const bf16x8*)&Ks[r1 * 128 + c1 * 8];
            s1 = __builtin_amdgcn_mfma_f32_32x32x16_bf16(kf1, qf[ds], s1, 0, 0, 0);
        }
        if (kb == kbw) {
            const int qg = q0w + q31;
            #pragma unroll
            for (int r = 0; r < 16; r++) {
                int kpos = (r & 3) + 8 * (r >> 2) + 4 * h2;
                s0[r] = (kb * 64 + kpos > qg) ? -1e30f : s0[r];
                s1[r] = (kb * 64 + 32 + kpos > qg) ? -1e30f : s1[r];
            }
        }
        float pm = -1e30f;
        #pragma unroll
        for (int r = 0; r < 16; r++) pm = fmaxf(pm, fmaxf(s0[r], s1[r]));
        pm = fmaxf(pm, __shfl_xor(pm, 32));
        bool grow = pm > m_r + 8.f;
        if (__any(grow)) {
            float mn = fmaxf(m_r, pm);
            float sc = __expf(m_r - mn);
            l_r *= sc;
            float scr[16];
            #pragma unroll
            for (int r = 0; r < 16; r++) scr[r] = __shfl(sc, (r & 3) + 8 * (r >> 2) + 4 * h2);
            #pragma unroll
            for (int nt = 0; nt < 4; nt++)
                #pragma unroll
                for (int r = 0; r < 16; r++) oacc[nt][r] *= scr[r];
            m_r = mn;
        }
        float sum = 0.f;
        #pragma unroll
        for (int r = 0; r < 16; r++) {
            s0[r] = __expf(s0[r] - m_r); sum += s0[r];
            s1[r] = __expf(s1[r] - m_r); sum += s1[r];
        }
        sum += __shfl_xor(sum, 32);
        l_r += sum;
        unsigned ow0[8], ow1[8];
        #pragma unroll
        for (int a = 0; a < 4; a++) {
            ow0[a * 2 + 0] = cvtpk(s0[4 * a + 0], s0[4 * a + 1]);
            ow0[a * 2 + 1] = cvtpk(s0[4 * a + 2], s0[4 * a + 3]);
            ow1[a * 2 + 0] = cvtpk(s1[4 * a + 0], s1[4 * a + 1]);
            ow1[a * 2 + 1] = cvtpk(s1[4 * a + 2], s1[4 * a + 3]);
        }
        unsigned pw0[8], pw1[8];
        #pragma unroll
        for (int i = 0; i < 8; i++) {
            pw0[i] = __shfl_xor((int)ow0[i], 32);
            pw1[i] = __shfl_xor((int)ow1[i], 32);
        }
        bf16x8 pf[4];
        const bool lo = (h2 == 0);
        #pragma unroll
        for (int sub = 0; sub < 2; sub++) {
            int b0 = 2 * sub, b1 = 2 * sub + 1;
            u32x4 t0, t1;
            t0.x = lo ? ow0[b0 * 2 + 0] : pw0[b1 * 2 + 0];
            t0.y = lo ? ow0[b0 * 2 + 1] : pw0[b1 * 2 + 1];
            t0.z = lo ? pw0[b0 * 2 + 0] : ow0[b1 * 2 + 0];
            t0.w = lo ? pw0[b0 * 2 + 1] : ow0[b1 * 2 + 1];
            pf[sub] = __builtin_bit_cast(bf16x8, t0);
            t1.x = lo ? ow1[b0 * 2 + 0] : pw1[b1 * 2 + 0];
            t1.y = lo ? ow1[b0 * 2 + 1] : pw1[b1 * 2 + 1];
            t1.z = lo ? pw1[b0 * 2 + 0] : ow1[b1 * 2 + 0];
            t1.w = lo ? pw1[b0 * 2 + 1] : ow1[b1 * 2 + 1];
            pf[2 + sub] = __builtin_bit_cast(bf16x8, t1);
        }
        #pragma unroll
        for (int nt = 0; nt < 4; nt++) {
            int vr2 = nt * 32 + q31;
            #pragma unroll
            for (int kt16 = 0; kt16 < 4; kt16++) {
                int vc2 = (kt16 * 2 + h2) ^ (vr2 & 7);
                bf16x8 vf = *(const bf16x8*)&Vs[vr2 * 64 + vc2 * 8];
                oacc[nt] = __builtin_amdgcn_mfma_f32_32x32x16_bf16(pf[kt16], vf, oacc[nt], 0, 0, 0);
            }
        }
    }
    float inv = 1.0f / l_r;
    float invr[16];
    #pragma unroll
    for (int r = 0; r < 16; r++) invr[r] = __shfl(inv, (r & 3) + 8 * (r >> 2) + 4 * h2);
    #pragma unroll
    for (int nt = 0; nt < 4; nt++)
        #pragma unroll
        for (int r = 0; r < 16; r++) {
            int qg = q0w + (r & 3) + 8 * (r >> 2) + 4 * h2;
            O[(size_t)qg * HDIM + h * DHEAD + nt * 32 + q31] = f2bf(oacc[nt][r] * invr[r]);
        }
}

extern "C" void kernel_launch(void* const* d_in, const int* in_sizes, int n_in,
                              void* d_out, int out_size, void* d_ws, size_t ws_size,
                              hipStream_t stream) {
    const float* hs  = (const float*)d_in[0];
    const float* lnw = (const float*)d_in[1];
    const float* lnb = (const float*)d_in[2];
    const float* wq  = (const float*)d_in[3];
    const float* wk  = (const float*)d_in[4];
    const float* wv  = (const float*)d_in[5];
    const float* wo  = (const float*)d_in[6];
    float* out = (float*)d_out;

    char* ws = (char*)d_ws;
    size_t off = 0;
    auto alloc = [&](size_t bytes) {
        void* p = ws + off;
        off += (bytes + 255) & ~(size_t)255;
        return p;
    };
    unsigned short* xb   = (unsigned short*)alloc((size_t)SEQ * HDIM * 2);
    // wqT/wkT/wvT contiguous -> fused [6144][4096] B matrix
    unsigned short* wqT  = (unsigned short*)alloc((size_t)HDIM * (NQH * DHEAD) * 2);
    unsigned short* wkT  = (unsigned short*)alloc((size_t)HDIM * (NKVH * DHEAD) * 2);
    unsigned short* wvT  = (unsigned short*)alloc((size_t)HDIM * (NKVH * DHEAD) * 2);
    unsigned short* woT  = (unsigned short*)alloc((size_t)(NQH * DHEAD) * HDIM * 2);
    float* qkvf          = (float*)alloc((size_t)SEQ * QKVN * 4);
    unsigned short* qbuf = (unsigned short*)alloc((size_t)NQH * SEQ * DHEAD * 2);
    unsigned short* kbuf = (unsigned short*)alloc((size_t)NKVH * SEQ * DHEAD * 2);
    unsigned short* vbt  = (unsigned short*)alloc((size_t)NKVH * DHEAD * SEQ * 2);
    unsigned short* attnb = (unsigned short*)qkvf;  // reuse fused-fp32 region after rope/v-transpose

    dim3 tb(32, 8);
    transpose_convert<<<dim3(4096 / 32, 4096 / 32), tb, 0, stream>>>(wq, wqT, 4096, 4096);
    transpose_convert<<<dim3(1024 / 32, 4096 / 32), tb, 0, stream>>>(wk, wkT, 4096, 1024);
    transpose_convert<<<dim3(1024 / 32, 4096 / 32), tb, 0, stream>>>(wv, wvT, 4096, 1024);
    transpose_convert<<<dim3(4096 / 32, 4096 / 32), tb, 0, stream>>>(wo, woT, 4096, 4096);

    layernorm_kernel<<<SEQ, 256, 0, stream>>>(hs, lnw, lnb, xb);

    // fused QKV projection: [2048][4096] x [6144][4096]^T -> [2048][6144]
    gemm8p<<<(2048 / 256) * (QKVN / 256), 512, 0, stream>>>(
        xb, wqT, qkvf, QKVN, 4096, 4096, QKVN / 256, (2048 / 256) * (QKVN / 256), 0, 0);

    rope_convert<<<dim3(SEQ, NQH + NKVH), 64, 0, stream>>>(qkvf, qbuf, kbuf);
    transpose_v<<<dim3(SEQ / 32, DHEAD / 32, NKVH), tb, 0, stream>>>(qkvf, vbt);

    // swapped-QK attention: grid = 32 heads x 16 q-slabs (128 rows each), 4 warps/block
    attention_kernel<<<NQH * 16, 256, 0, stream>>>(qbuf, kbuf, vbt, attnb);

    // O-proj: full K=4096, grid 8 x 32 = 256 blocks exactly, no split-K, no reduce
    gemm8n<<<(2048 / 256) * (4096 / 128), 512, 0, stream>>>(
        attnb, woT, out, 4096, 4096, 4096, 4096 / 128);
}